// Round 17
// baseline (187.547 us; speedup 1.0000x reference)
//
#include <hip/hip_runtime.h>
#include <hip/hip_bf16.h>
#include <math.h>

typedef __bf16 bf16;
typedef bf16  bf16x8 __attribute__((ext_vector_type(8)));
typedef float f32x4  __attribute__((ext_vector_type(4)));

#define MFMA16(a,b,c) __builtin_amdgcn_mfma_f32_16x16x32_bf16(a,b,c,0,0,0)
#define FENCE() do { asm volatile("s_waitcnt lgkmcnt(0)" ::: "memory"); __builtin_amdgcn_sched_barrier(0); } while(0)
#define PRIO_HI() __builtin_amdgcn_s_setprio(1)
#define PRIO_LO() __builtin_amdgcn_s_setprio(0)

__device__ __forceinline__ f32x4 ld4(const float* p) { return *(const f32x4*)p; }

__device__ __forceinline__ bf16x8 cvt8(const f32x4& a, const f32x4& b) {
  bf16x8 v;
  v[0]=(bf16)a[0]; v[1]=(bf16)a[1]; v[2]=(bf16)a[2]; v[3]=(bf16)a[3];
  v[4]=(bf16)b[0]; v[5]=(bf16)b[1]; v[6]=(bf16)b[2]; v[7]=(bf16)b[3];
  return v;
}

// fast GELU (tanh form via HW exp)
__device__ __forceinline__ float gelu_fast(float x) {
  const float z = 1.5957691216f * (x + 0.044715f * x * x * x);
  return x / (1.0f + __expf(-z));
}

// ---------------- prep: fp32 weights -> bf16 ----------------
__global__ void prep_weights(const float* __restrict__ qkv_w, const float* __restrict__ proj_w,
                             const float* __restrict__ fc1_w, const float* __restrict__ fc2_w,
                             bf16* __restrict__ qkv_wb, bf16* __restrict__ proj_wb,
                             bf16* __restrict__ fc1_wb, bf16* __restrict__ fc2_wb) {
  int i = blockIdx.x * 256 + threadIdx.x;
  if (i < 196608) qkv_wb[i] = (bf16)qkv_w[i];
  if (i <  65536) proj_wb[i] = (bf16)proj_w[i];
  if (i < 262144) { fc1_wb[i] = (bf16)fc1_w[i]; fc2_wb[i] = (bf16)fc2_w[i]; }
}

// ---------------- prep: CPB MLP -> tab[225][8] ----------------
__global__ void prep_tab(const float* __restrict__ w1, const float* __restrict__ b1,
                         const float* __restrict__ w2, float* __restrict__ tab_g) {
  const int c = blockIdx.x;
  const int a = c / 15, bq = c % 15;
  const float g0 = (float)(a - 7) * (8.0f / 7.0f);
  const float g1 = (float)(bq - 7) * (8.0f / 7.0f);
  const float t0 = copysignf(log2f(fabsf(g0) + 1.0f) * (1.0f/3.0f), g0);
  const float t1 = copysignf(log2f(fabsf(g1) + 1.0f) * (1.0f/3.0f), g1);
  const int lane = threadIdx.x;
  float acc[8] = {0.f,0.f,0.f,0.f,0.f,0.f,0.f,0.f};
#pragma unroll
  for (int e = 0; e < 8; ++e) {
    const int h = lane*8 + e;
    float hv = t0 * w1[h*3 + 0] + t1 * w1[h*3 + 1] + b1[h];
    hv = fmaxf(hv, 0.0f);
#pragma unroll
    for (int j = 0; j < 8; ++j) acc[j] += hv * w2[j*512 + h];
  }
#pragma unroll
  for (int j = 0; j < 8; ++j) {
    acc[j] += __shfl_xor(acc[j], 1);
    acc[j] += __shfl_xor(acc[j], 2);
    acc[j] += __shfl_xor(acc[j], 4);
    acc[j] += __shfl_xor(acc[j], 8);
    acc[j] += __shfl_xor(acc[j], 16);
    acc[j] += __shfl_xor(acc[j], 32);
  }
  if (lane == 0) {
#pragma unroll
    for (int j = 0; j < 8; ++j) tab_g[c*8 + j] = acc[j];
  }
}

// ---------------- prep: expand tab -> bias_t[8][ct=64][rt=64] (TRANSPOSED) ----------------
__global__ void prep_expand(const float* __restrict__ tab_g, float* __restrict__ bias_t) {
  const int idx = blockIdx.x * 256 + threadIdx.x;
  const int head = idx >> 12, ct = (idx >> 6) & 63, rt = idx & 63;
  const int dy = (rt >> 3) - (ct >> 3), dx = (rt & 7) - (ct & 7);
  const float v = tab_g[((dy + 7)*15 + (dx + 7))*8 + head];
  bias_t[idx] = 16.0f / (1.0f + __expf(-v));
}

// ---------------- FULLY FUSED Swin block ----------------
// one block per (batch, window); 8 waves; wave = head. LDS 64KB (2 blocks/CU).
// launch_bounds min-BLOCKS=2 -> 128-VGPR budget.
__launch_bounds__(512, 2)
__global__ void k_fused(const float* __restrict__ x,
                        const bf16* __restrict__ qkv_wb, const float* __restrict__ qkv_b,
                        const float* __restrict__ nq_w, const float* __restrict__ nk_w,
                        const bf16* __restrict__ proj_wb, const float* __restrict__ proj_b,
                        const float* __restrict__ n1w, const float* __restrict__ n1b,
                        const float* __restrict__ bias_t,
                        const bf16* __restrict__ fc1_wb, const float* __restrict__ fc1_b,
                        const bf16* __restrict__ fc2_wb, const float* __restrict__ fc2_b,
                        const float* __restrict__ n2w, const float* __restrict__ n2b,
                        float* __restrict__ out) {
  __shared__ __align__(16) unsigned char SM[65536];
  const int tid  = threadIdx.x;
  const int wv   = tid >> 6;
  const int lane = tid & 63;
  const int lm   = lane & 15;
  const int lg   = lane >> 4;
  const int lk   = lg << 3;
  const int blk  = blockIdx.x;
  const int b    = blk >> 6;
  const int win  = blk & 63;
  const int wy   = win >> 3, wx = win & 7;
  const int h    = wv;
  const int SB   = 32768 + wv*4096;   // wave-private 4KB bounce strip
  const int LNB  = 32768;             // LN stats overlay (strips / HS region)
  const int HS   = 32768;             // MLP h-chunk buffer

  // ---- stage shifted-window x tile -> bf16 LDS [64][256] XOR-swizzled (XA = 0..32K)
  {
    const int t = tid >> 3, q8 = tid & 7;
    const int iy = t >> 3, ix = t & 7;
    const int gh = (wy*8 + iy + 4) & 63, gw = (wx*8 + ix + 4) & 63;
    const float* src = x + (size_t)(b*4096 + gh*64 + gw) * 256 + q8*32;
#pragma unroll
    for (int i = 0; i < 4; ++i) {
      f32x4 f0 = ld4(src + i*8);
      f32x4 f1 = ld4(src + i*8 + 4);
      *(bf16x8*)(SM + ((t*512 + (q8*32 + i*8)*2) ^ ((t&7)<<4))) = cvt8(f0, f1);
    }
  }
  __syncthreads();   // B0

  bf16x8 qf[4], kf[4], vb[2][2];

  // ---- QKV pass0: q + k (d 0..32) for this head
  {
    const int jq[4] = { h*32 + lm, h*32 + 16 + lm, 256 + h*32 + lm, 256 + h*32 + 16 + lm };
    f32x4 acc[4][4] = {};
    PRIO_HI();
#pragma unroll
    for (int kk = 0; kk < 8; ++kk) {
      const int ko = kk*32 + lk;
      bf16x8 a[4], bb[4];
#pragma unroll
      for (int m = 0; m < 4; ++m) {
        const int t = m*16 + lm;
        a[m] = *(const bf16x8*)(SM + ((t*512 + ko*2) ^ ((t&7)<<4)));
      }
#pragma unroll
      for (int n = 0; n < 4; ++n)
        bb[n] = *(const bf16x8*)(qkv_wb + jq[n]*256 + ko);
#pragma unroll
      for (int m = 0; m < 4; ++m)
#pragma unroll
        for (int n = 0; n < 4; ++n)
          acc[m][n] = MFMA16(a[m], bb[n], acc[m][n]);
    }
    PRIO_LO();
    float bj[4];
#pragma unroll
    for (int n = 0; n < 4; ++n) bj[n] = qkv_b[jq[n]];
#pragma unroll
    for (int m = 0; m < 4; ++m)
#pragma unroll
      for (int n = 0; n < 4; ++n)
#pragma unroll
        for (int r = 0; r < 4; ++r) acc[m][n][r] += bj[n];
    const float nqw0 = nq_w[lm], nqw1 = nq_w[16+lm];
    const float nkw0 = nk_w[lm], nkw1 = nk_w[16+lm];
#pragma unroll
    for (int m = 0; m < 4; ++m)
#pragma unroll
      for (int r = 0; r < 4; ++r) {
        float q0 = acc[m][0][r], q1 = acc[m][1][r];
        float k0 = acc[m][2][r], k1 = acc[m][3][r];
        float sq = q0*q0 + q1*q1, sk = k0*k0 + k1*k1;
        sq += __shfl_xor(sq, 1); sk += __shfl_xor(sk, 1);
        sq += __shfl_xor(sq, 2); sk += __shfl_xor(sk, 2);
        sq += __shfl_xor(sq, 4); sk += __shfl_xor(sk, 4);
        sq += __shfl_xor(sq, 8); sk += __shfl_xor(sk, 8);
        const float scq = rsqrtf(sq * (1.0f/32.0f) + 1.1920929e-07f);
        const float sck = rsqrtf(sk * (1.0f/32.0f) + 1.1920929e-07f);
        acc[m][0][r] = q0*scq*nqw0; acc[m][1][r] = q1*scq*nqw1;
        acc[m][2][r] = k0*sck*nkw0; acc[m][3][r] = k1*sck*nkw1;
      }
#pragma unroll
    for (int m = 0; m < 4; ++m)
#pragma unroll
      for (int n = 0; n < 2; ++n)
#pragma unroll
        for (int r = 0; r < 4; ++r)
          *(bf16*)(SM + SB + m*1024 + (lg*4+r)*16 + (n*2 + (lm>>3))*256 + (lm&7)*2)
            = (bf16)acc[m][n][r];
    FENCE();
#pragma unroll
    for (int m = 0; m < 4; ++m)
      qf[m] = *(const bf16x8*)(SM + SB + m*1024 + lane*16);
    FENCE();
#pragma unroll
    for (int m = 0; m < 4; ++m)
#pragma unroll
      for (int n = 0; n < 2; ++n)
#pragma unroll
        for (int r = 0; r < 4; ++r)
          *(bf16*)(SM + SB + m*1024 + (lg*4+r)*16 + (n*2 + (lm>>3))*256 + (lm&7)*2)
            = (bf16)acc[m][2+n][r];
    FENCE();
#pragma unroll
    for (int m = 0; m < 4; ++m)
      kf[m] = *(const bf16x8*)(SM + SB + m*1024 + lane*16);
    FENCE();
  }

  // ---- QKV pass1: v for this head
  {
    const int jv[2] = { 512 + h*32 + lm, 512 + h*32 + 16 + lm };
    f32x4 vacc[4][2] = {};
    PRIO_HI();
#pragma unroll
    for (int kk = 0; kk < 8; ++kk) {
      const int ko = kk*32 + lk;
      bf16x8 a[4], bb[2];
#pragma unroll
      for (int m = 0; m < 4; ++m) {
        const int t = m*16 + lm;
        a[m] = *(const bf16x8*)(SM + ((t*512 + ko*2) ^ ((t&7)<<4)));
      }
#pragma unroll
      for (int n = 0; n < 2; ++n)
        bb[n] = *(const bf16x8*)(qkv_wb + jv[n]*256 + ko);
#pragma unroll
      for (int m = 0; m < 4; ++m)
#pragma unroll
        for (int n = 0; n < 2; ++n)
          vacc[m][n] = MFMA16(a[m], bb[n], vacc[m][n]);
    }
    PRIO_LO();
    float bj[2] = { qkv_b[jv[0]], qkv_b[jv[1]] };
#pragma unroll
    for (int m = 0; m < 4; ++m)
#pragma unroll
      for (int n = 0; n < 2; ++n)
#pragma unroll
        for (int r = 0; r < 4; ++r)
          *(bf16*)(SM + SB + (n*2 + (m>>1))*1024 + lm*16
                   + ((m&1)*2 + ((lg*4+r)>>3))*256 + ((lg*4+r)&7)*2)
            = (bf16)(vacc[m][n][r] + bj[n]);
    FENCE();
#pragma unroll
    for (int nf = 0; nf < 2; ++nf)
#pragma unroll
      for (int ks = 0; ks < 2; ++ks)
        vb[nf][ks] = *(const bf16x8*)(SM + SB + (nf*2+ks)*1024 + lane*16);
    FENCE();
  }
  __syncthreads();   // B1

  // ---- QK^T + bias + mask + softmax
  f32x4 s[4][4];
  PRIO_HI();
#pragma unroll
  for (int m = 0; m < 4; ++m)
#pragma unroll
    for (int n = 0; n < 4; ++n) {
      f32x4 z = {};
      s[m][n] = MFMA16(qf[m], kf[n], z);
    }
  PRIO_LO();
#pragma unroll
  for (int n = 0; n < 4; ++n) {
    const int ct = n*16 + lm;
    const int idc = ((wy==7) ? (((ct>>3) < 4) ? 1 : 2) : 0) * 3
                  + ((wx==7) ? (((ct&7)  < 4) ? 1 : 2) : 0);
#pragma unroll
    for (int m = 0; m < 4; ++m) {
      const f32x4 bt = *(const f32x4*)(bias_t + h*4096 + ct*64 + m*16 + lg*4);
#pragma unroll
      for (int r = 0; r < 4; ++r) {
        const int rt = m*16 + lg*4 + r;
        const int idr = ((wy==7) ? (((rt>>3) < 4) ? 1 : 2) : 0) * 3
                      + ((wx==7) ? (((rt&7)  < 4) ? 1 : 2) : 0);
        float add = bt[r];
        if (idr != idc) add -= 100.0f;
        s[m][n][r] += add;
      }
    }
  }
#pragma unroll
  for (int m = 0; m < 4; ++m)
#pragma unroll
    for (int r = 0; r < 4; ++r) {
      float v0 = s[m][0][r], v1 = s[m][1][r], v2 = s[m][2][r], v3 = s[m][3][r];
      float mx = fmaxf(fmaxf(v0, v1), fmaxf(v2, v3));
      mx = fmaxf(mx, __shfl_xor(mx, 1));
      mx = fmaxf(mx, __shfl_xor(mx, 2));
      mx = fmaxf(mx, __shfl_xor(mx, 4));
      mx = fmaxf(mx, __shfl_xor(mx, 8));
      v0 = __expf(v0 - mx); v1 = __expf(v1 - mx);
      v2 = __expf(v2 - mx); v3 = __expf(v3 - mx);
      float sm = v0 + v1 + v2 + v3;
      sm += __shfl_xor(sm, 1);
      sm += __shfl_xor(sm, 2);
      sm += __shfl_xor(sm, 4);
      sm += __shfl_xor(sm, 8);
      const float inv = 1.0f / sm;
      s[m][0][r] = v0*inv; s[m][1][r] = v1*inv; s[m][2][r] = v2*inv; s[m][3][r] = v3*inv;
    }

  // ---- PV through strip in two 32-row halves
  f32x4 yacc[4][2] = {};
#pragma unroll
  for (int mh = 0; mh < 2; ++mh) {
#pragma unroll
    for (int ml = 0; ml < 2; ++ml)
#pragma unroll
      for (int n = 0; n < 4; ++n)
#pragma unroll
        for (int r = 0; r < 4; ++r)
          *(bf16*)(SM + SB + (ml*2 + (n>>1))*1024 + (lg*4+r)*16
                   + ((n&1)*2 + (lm>>3))*256 + (lm&7)*2)
            = (bf16)s[mh*2+ml][n][r];
    FENCE();
    bf16x8 pa[2][2];
#pragma unroll
    for (int ml = 0; ml < 2; ++ml)
#pragma unroll
      for (int ks = 0; ks < 2; ++ks)
        pa[ml][ks] = *(const bf16x8*)(SM + SB + (ml*2+ks)*1024 + lane*16);
    FENCE();
    PRIO_HI();
#pragma unroll
    for (int ml = 0; ml < 2; ++ml)
#pragma unroll
      for (int ks = 0; ks < 2; ++ks)
#pragma unroll
        for (int nf = 0; nf < 2; ++nf)
          yacc[mh*2+ml][nf] = MFMA16(pa[ml][ks], vb[nf][ks], yacc[mh*2+ml][nf]);
    PRIO_LO();
  }

  // ---- y (head h) -> y_all in XA area
#pragma unroll
  for (int m = 0; m < 4; ++m)
#pragma unroll
    for (int nf = 0; nf < 2; ++nf)
#pragma unroll
      for (int r = 0; r < 4; ++r) {
        const int t = m*16 + lg*4 + r;
        const int c = h*32 + nf*16 + lm;
        *(bf16*)(SM + ((t*512 + c*2) ^ ((t&7)<<4))) = (bf16)yacc[m][nf][r];
      }
  __syncthreads();   // B2

  // ---- proj: wave covers 32 cols, K=256
  f32x4 pacc[4][2] = {};
  PRIO_HI();
#pragma unroll
  for (int kk = 0; kk < 8; ++kk) {
    const int ko = kk*32 + lk;
    bf16x8 a[4], bb[2];
#pragma unroll
    for (int m = 0; m < 4; ++m) {
      const int t = m*16 + lm;
      a[m] = *(const bf16x8*)(SM + ((t*512 + ko*2) ^ ((t&7)<<4)));
    }
#pragma unroll
    for (int n = 0; n < 2; ++n) {
      const int j = wv*32 + n*16 + lm;
      bb[n] = *(const bf16x8*)(proj_wb + j*256 + ko);
    }
#pragma unroll
    for (int m = 0; m < 4; ++m)
#pragma unroll
      for (int n = 0; n < 2; ++n)
        pacc[m][n] = MFMA16(a[m], bb[n], pacc[m][n]);
  }
  PRIO_LO();
  {
    const float b0 = proj_b[wv*32 + lm], b1 = proj_b[wv*32 + 16 + lm];
#pragma unroll
    for (int m = 0; m < 4; ++m)
#pragma unroll
      for (int r = 0; r < 4; ++r) { pacc[m][0][r] += b0; pacc[m][1][r] += b1; }
  }

  // ---- LN1 stats (fragment reduce)
#pragma unroll
  for (int m = 0; m < 4; ++m)
#pragma unroll
    for (int r = 0; r < 4; ++r) {
      float p  = pacc[m][0][r] + pacc[m][1][r];
      float ps = pacc[m][0][r]*pacc[m][0][r] + pacc[m][1][r]*pacc[m][1][r];
      p  += __shfl_xor(p, 1);  ps += __shfl_xor(ps, 1);
      p  += __shfl_xor(p, 2);  ps += __shfl_xor(ps, 2);
      p  += __shfl_xor(p, 4);  ps += __shfl_xor(ps, 4);
      p  += __shfl_xor(p, 8);  ps += __shfl_xor(ps, 8);
      if (lm == 0) {
        const int row = m*16 + lg*4 + r;
        *(float*)(SM + LNB + row*32 + wv*4) = p;
        *(float*)(SM + LNB + 2048 + row*32 + wv*4) = ps;
      }
    }
  __syncthreads();   // B3
  if (tid < 64) {
    const int row = tid;
    f32x4 s0 = *(const f32x4*)(SM + LNB + row*32);
    f32x4 s1 = *(const f32x4*)(SM + LNB + row*32 + 16);
    f32x4 q0 = *(const f32x4*)(SM + LNB + 2048 + row*32);
    f32x4 q1 = *(const f32x4*)(SM + LNB + 2048 + row*32 + 16);
    const float sm_ = s0[0]+s0[1]+s0[2]+s0[3]+s1[0]+s1[1]+s1[2]+s1[3];
    const float qq  = q0[0]+q0[1]+q0[2]+q0[3]+q1[0]+q1[1]+q1[2]+q1[3];
    const float mu  = sm_ * (1.0f/256.0f);
    const float var = qq * (1.0f/256.0f) - mu*mu;
    float2 mi; mi.x = mu; mi.y = rsqrtf(var + 1e-5f);
    *(float2*)(SM + LNB + 4096 + row*8) = mi;
  }
  __syncthreads();   // B4

  // ---- LN1 apply + x shortcut, x1 stays in FRAG REGISTERS (pacc); bf16 copy -> XA
  {
    const float w0 = n1w[wv*32 + lm],  w1 = n1w[wv*32 + 16 + lm];
    const float b0 = n1b[wv*32 + lm],  b1 = n1b[wv*32 + 16 + lm];
#pragma unroll
    for (int m = 0; m < 4; ++m)
#pragma unroll
      for (int r = 0; r < 4; ++r) {
        const int row = m*16 + lg*4 + r;
        const float2 mi = *(const float2*)(SM + LNB + 4096 + row*8);
        const int iy = row >> 3, ix = row & 7;
        const int gh = (wy*8 + iy + 4) & 63, gw = (wx*8 + ix + 4) & 63;
        const size_t gp = (size_t)(b*4096 + gh*64 + gw) * 256 + wv*32 + lm;
        pacc[m][0][r] = (pacc[m][0][r] - mi.x)*mi.y*w0 + b0 + x[gp];
        pacc[m][1][r] = (pacc[m][1][r] - mi.x)*mi.y*w1 + b1 + x[gp + 16];
      }
  }
  __syncthreads();   // B5: stats read done; XA (y_all) dead -> overwrite with x1 bf16
#pragma unroll
  for (int m = 0; m < 4; ++m)
#pragma unroll
    for (int r = 0; r < 4; ++r) {
      const int t = m*16 + lg*4 + r;
      const int c0 = wv*32 + lm, c1 = wv*32 + 16 + lm;
      *(bf16*)(SM + ((t*512 + c0*2) ^ ((t&7)<<4))) = (bf16)pacc[m][0][r];
      *(bf16*)(SM + ((t*512 + c1*2) ^ ((t&7)<<4))) = (bf16)pacc[m][1][r];
    }
  __syncthreads();   // B6: XA = x1 bf16 ready; HS region free

  // ================= MLP phase (same 64 tokens, in-block) =================
  f32x4 acc2[4][2] = {};
#pragma unroll 1
  for (int kc = 0; kc < 4; ++kc) {
    f32x4 acc1[4][2] = {};
    PRIO_HI();
#pragma unroll
    for (int kk = 0; kk < 8; ++kk) {
      const int ko = kk*32 + lk;
      bf16x8 a[4], bb[2];
#pragma unroll
      for (int m = 0; m < 4; ++m) {
        const int t = m*16 + lm;
        a[m] = *(const bf16x8*)(SM + ((t*512 + ko*2) ^ ((t&7)<<4)));
      }
#pragma unroll
      for (int n = 0; n < 2; ++n) {
        const int j = kc*256 + wv*32 + n*16 + lm;
        bb[n] = *(const bf16x8*)(fc1_wb + j*256 + ko);
      }
#pragma unroll
      for (int m = 0; m < 4; ++m)
#pragma unroll
        for (int n = 0; n < 2; ++n)
          acc1[m][n] = MFMA16(a[m], bb[n], acc1[m][n]);
    }
    PRIO_LO();
    // fast GELU + bias -> HS
#pragma unroll
    for (int n = 0; n < 2; ++n) {
      const float bj = fc1_b[kc*256 + wv*32 + n*16 + lm];
      const int cb = wv*64 + n*32 + lm*2;
#pragma unroll
      for (int m = 0; m < 4; ++m)
#pragma unroll
        for (int r = 0; r < 4; ++r) {
          const int t = m*16 + lg*4 + r;
          const float v = gelu_fast(acc1[m][n][r] + bj);
          *(bf16*)(SM + HS + ((t*512 + cb) ^ ((t&7)<<4))) = (bf16)v;
        }
    }
    __syncthreads();
    // fc2 partial
    PRIO_HI();
#pragma unroll
    for (int kk = 0; kk < 8; ++kk) {
      const int ko = kk*32 + lk;
      bf16x8 a[4], bb[2];
#pragma unroll
      for (int m = 0; m < 4; ++m) {
        const int t = m*16 + lm;
        a[m] = *(const bf16x8*)(SM + HS + ((t*512 + ko*2) ^ ((t&7)<<4)));
      }
#pragma unroll
      for (int n = 0; n < 2; ++n) {
        const int j = wv*32 + n*16 + lm;
        bb[n] = *(const bf16x8*)(fc2_wb + (size_t)j*1024 + kc*256 + ko);
      }
#pragma unroll
      for (int m = 0; m < 4; ++m)
#pragma unroll
        for (int n = 0; n < 2; ++n)
          acc2[m][n] = MFMA16(a[m], bb[n], acc2[m][n]);
    }
    PRIO_LO();
    __syncthreads();
  }

  // fc2 bias
  {
    const float b0 = fc2_b[wv*32 + lm], b1 = fc2_b[wv*32 + 16 + lm];
#pragma unroll
    for (int m = 0; m < 4; ++m)
#pragma unroll
      for (int r = 0; r < 4; ++r) { acc2[m][0][r] += b0; acc2[m][1][r] += b1; }
  }

  // ---- LN2 stats
#pragma unroll
  for (int m = 0; m < 4; ++m)
#pragma unroll
    for (int r = 0; r < 4; ++r) {
      float p  = acc2[m][0][r] + acc2[m][1][r];
      float ps = acc2[m][0][r]*acc2[m][0][r] + acc2[m][1][r]*acc2[m][1][r];
      p  += __shfl_xor(p, 1);  ps += __shfl_xor(ps, 1);
      p  += __shfl_xor(p, 2);  ps += __shfl_xor(ps, 2);
      p  += __shfl_xor(p, 4);  ps += __shfl_xor(ps, 4);
      p  += __shfl_xor(p, 8);  ps += __shfl_xor(ps, 8);
      if (lm == 0) {
        const int row = m*16 + lg*4 + r;
        *(float*)(SM + LNB + row*32 + wv*4) = p;
        *(float*)(SM + LNB + 2048 + row*32 + wv*4) = ps;
      }
    }
  __syncthreads();
  if (tid < 64) {
    const int row = tid;
    f32x4 s0 = *(const f32x4*)(SM + LNB + row*32);
    f32x4 s1 = *(const f32x4*)(SM + LNB + row*32 + 16);
    f32x4 q0 = *(const f32x4*)(SM + LNB + 2048 + row*32);
    f32x4 q1 = *(const f32x4*)(SM + LNB + 2048 + row*32 + 16);
    const float sm_ = s0[0]+s0[1]+s0[2]+s0[3]+s1[0]+s1[1]+s1[2]+s1[3];
    const float qq  = q0[0]+q0[1]+q0[2]+q0[3]+q1[0]+q1[1]+q1[2]+q1[3];
    const float mu  = sm_ * (1.0f/256.0f);
    const float var = qq * (1.0f/256.0f) - mu*mu;
    float2 mi; mi.x = mu; mi.y = rsqrtf(var + 1e-5f);
    *(float2*)(SM + LNB + 4096 + row*8) = mi;
  }
  __syncthreads();

  // cache LN2 stats in regs (Y2 overlay will clobber all LDS)
  float2 mi2[4][4];
#pragma unroll
  for (int m = 0; m < 4; ++m)
#pragma unroll
    for (int r = 0; r < 4; ++r)
      mi2[m][r] = *(const float2*)(SM + LNB + 4096 + (m*16 + lg*4 + r)*8);
  __syncthreads();   // all LDS dead

  // ---- out_frag = x1(regs) + LN2(acc2) -> Y2 fp32 [64][256] 2-key XOR swizzle
  {
    const float w0 = n2w[wv*32 + lm],  w1 = n2w[wv*32 + 16 + lm];
    const float b0 = n2b[wv*32 + lm],  b1 = n2b[wv*32 + 16 + lm];
#pragma unroll
    for (int m = 0; m < 4; ++m)
#pragma unroll
      for (int r = 0; r < 4; ++r) {
        const int t = m*16 + lg*4 + r;
        const int j0 = wv*32 + lm, j1 = wv*32 + 16 + lm;
        *(float*)(SM + t*1024 + ((j0*4) ^ (((t&7) ^ ((j0>>5)&7))<<4)))
          = (acc2[m][0][r] - mi2[m][r].x)*mi2[m][r].y*w0 + b0 + pacc[m][0][r];
        *(float*)(SM + t*1024 + ((j1*4) ^ (((t&7) ^ ((j1>>5)&7))<<4)))
          = (acc2[m][1][r] - mi2[m][r].x)*mi2[m][r].y*w1 + b1 + pacc[m][1][r];
      }
  }
  __syncthreads();

  // ---- epilogue: thread owns 128B run of a row -> store at unshifted position
  {
    const int t8 = tid >> 3, sub = tid & 7;
    const int key = ((t8&7) ^ sub) << 4;
    const int iy = t8 >> 3, ix = t8 & 7;
    const int gh = (wy*8 + iy + 4) & 63, gw = (wx*8 + ix + 4) & 63;
    const size_t grow = (size_t)(b*4096 + gh*64 + gw) * 256;
#pragma unroll
    for (int i = 0; i < 8; ++i) {
      const int c = sub*32 + i*4;
      f32x4 t4 = *(const f32x4*)(SM + t8*1024 + ((c*4) ^ key));
      *(f32x4*)(out + grow + c) = t4;
    }
  }
}

extern "C" void kernel_launch(void* const* d_in, const int* in_sizes, int n_in,
                              void* d_out, int out_size, void* d_ws, size_t ws_size,
                              hipStream_t stream) {
  const float* x      = (const float*)d_in[0];
  const float* qkv_w  = (const float*)d_in[1];
  const float* qkv_b  = (const float*)d_in[2];
  const float* nq_w   = (const float*)d_in[3];
  const float* nk_w   = (const float*)d_in[4];
  const float* cpb_w1 = (const float*)d_in[5];
  const float* cpb_b1 = (const float*)d_in[6];
  const float* cpb_w2 = (const float*)d_in[7];
  const float* proj_w = (const float*)d_in[8];
  const float* proj_b = (const float*)d_in[9];
  const float* n1w    = (const float*)d_in[10];
  const float* n1b    = (const float*)d_in[11];
  const float* fc1_w  = (const float*)d_in[12];
  const float* fc1_b  = (const float*)d_in[13];
  const float* fc2_w  = (const float*)d_in[14];
  const float* fc2_b  = (const float*)d_in[15];
  const float* n2w    = (const float*)d_in[16];
  const float* n2b    = (const float*)d_in[17];

  char* ws = (char*)d_ws;
  bf16*  qkv_wb  = (bf16*) (ws);                   //   393216 B
  bf16*  proj_wb = (bf16*) (ws + 393216);          //   131072 B
  bf16*  fc1_wb  = (bf16*) (ws + 524288);          //   524288 B
  bf16*  fc2_wb  = (bf16*) (ws + 1048576);         //   524288 B
  float* bias_t  = (float*)(ws + 1572864);         //   131072 B
  float* tab_g   = (float*)(ws + 1703936);         //     7200 B

  prep_weights<<<1024, 256, 0, stream>>>(qkv_w, proj_w, fc1_w, fc2_w,
                                         qkv_wb, proj_wb, fc1_wb, fc2_wb);
  prep_tab<<<225, 64, 0, stream>>>(cpb_w1, cpb_b1, cpb_w2, tab_g);
  prep_expand<<<128, 256, 0, stream>>>(tab_g, bias_t);
  k_fused<<<512, 512, 0, stream>>>(x, qkv_wb, qkv_b, nq_w, nk_w,
                                   proj_wb, proj_b, n1w, n1b, bias_t,
                                   fc1_wb, fc1_b, fc2_wb, fc2_b, n2w, n2b,
                                   (float*)d_out);
}

// Round 18
// 183.874 us; speedup vs baseline: 1.0200x; 1.0200x over previous
//
#include <hip/hip_runtime.h>
#include <hip/hip_bf16.h>
#include <math.h>

typedef __bf16 bf16;
typedef bf16  bf16x8 __attribute__((ext_vector_type(8)));
typedef float f32x4  __attribute__((ext_vector_type(4)));

#define MFMA16(a,b,c) __builtin_amdgcn_mfma_f32_16x16x32_bf16(a,b,c,0,0,0)
#define FENCE() do { asm volatile("s_waitcnt lgkmcnt(0)" ::: "memory"); __builtin_amdgcn_sched_barrier(0); } while(0)

__device__ __forceinline__ f32x4 ld4(const float* p) { return *(const f32x4*)p; }

__device__ __forceinline__ bf16x8 cvt8(const f32x4& a, const f32x4& b) {
  bf16x8 v;
  v[0]=(bf16)a[0]; v[1]=(bf16)a[1]; v[2]=(bf16)a[2]; v[3]=(bf16)a[3];
  v[4]=(bf16)b[0]; v[5]=(bf16)b[1]; v[6]=(bf16)b[2]; v[7]=(bf16)b[3];
  return v;
}

// fast GELU (tanh form via HW exp)
__device__ __forceinline__ float gelu_fast(float x) {
  const float z = 1.5957691216f * (x + 0.044715f * x * x * x);
  return x / (1.0f + __expf(-z));
}

// ---------------- prep: fp32 weights -> bf16 ----------------
__global__ void prep_weights(const float* __restrict__ qkv_w, const float* __restrict__ proj_w,
                             const float* __restrict__ fc1_w, const float* __restrict__ fc2_w,
                             bf16* __restrict__ qkv_wb, bf16* __restrict__ proj_wb,
                             bf16* __restrict__ fc1_wb, bf16* __restrict__ fc2_wb) {
  int i = blockIdx.x * 256 + threadIdx.x;
  if (i < 196608) qkv_wb[i] = (bf16)qkv_w[i];
  if (i <  65536) proj_wb[i] = (bf16)proj_w[i];
  if (i < 262144) { fc1_wb[i] = (bf16)fc1_w[i]; fc2_wb[i] = (bf16)fc2_w[i]; }
}

// ---------------- prep: CPB MLP -> tab[225][8] ----------------
__global__ void prep_tab(const float* __restrict__ w1, const float* __restrict__ b1,
                         const float* __restrict__ w2, float* __restrict__ tab_g) {
  const int c = blockIdx.x;
  const int a = c / 15, bq = c % 15;
  const float g0 = (float)(a - 7) * (8.0f / 7.0f);
  const float g1 = (float)(bq - 7) * (8.0f / 7.0f);
  const float t0 = copysignf(log2f(fabsf(g0) + 1.0f) * (1.0f/3.0f), g0);
  const float t1 = copysignf(log2f(fabsf(g1) + 1.0f) * (1.0f/3.0f), g1);
  const int lane = threadIdx.x;
  float acc[8] = {0.f,0.f,0.f,0.f,0.f,0.f,0.f,0.f};
#pragma unroll
  for (int e = 0; e < 8; ++e) {
    const int h = lane*8 + e;
    float hv = t0 * w1[h*3 + 0] + t1 * w1[h*3 + 1] + b1[h];
    hv = fmaxf(hv, 0.0f);
#pragma unroll
    for (int j = 0; j < 8; ++j) acc[j] += hv * w2[j*512 + h];
  }
#pragma unroll
  for (int j = 0; j < 8; ++j) {
    acc[j] += __shfl_xor(acc[j], 1);
    acc[j] += __shfl_xor(acc[j], 2);
    acc[j] += __shfl_xor(acc[j], 4);
    acc[j] += __shfl_xor(acc[j], 8);
    acc[j] += __shfl_xor(acc[j], 16);
    acc[j] += __shfl_xor(acc[j], 32);
  }
  if (lane == 0) {
#pragma unroll
    for (int j = 0; j < 8; ++j) tab_g[c*8 + j] = acc[j];
  }
}

// ---------------- prep: expand tab -> bias_t[8][ct=64][rt=64] (TRANSPOSED) ----------------
__global__ void prep_expand(const float* __restrict__ tab_g, float* __restrict__ bias_t) {
  const int idx = blockIdx.x * 256 + threadIdx.x;
  const int head = idx >> 12, ct = (idx >> 6) & 63, rt = idx & 63;
  const int dy = (rt >> 3) - (ct >> 3), dx = (rt & 7) - (ct & 7);
  const float v = tab_g[((dy + 7)*15 + (dx + 7))*8 + head];
  bias_t[idx] = 16.0f / (1.0f + __expf(-v));
}

// ---------------- FULLY FUSED Swin block ----------------
// one block per (batch, window); 8 waves; wave = head. LDS 64KB (2 blocks/CU).
// launch_bounds min-BLOCKS=2 -> 128-VGPR budget.
__launch_bounds__(512, 2)
__global__ void k_fused(const float* __restrict__ x,
                        const bf16* __restrict__ qkv_wb, const float* __restrict__ qkv_b,
                        const float* __restrict__ nq_w, const float* __restrict__ nk_w,
                        const bf16* __restrict__ proj_wb, const float* __restrict__ proj_b,
                        const float* __restrict__ n1w, const float* __restrict__ n1b,
                        const float* __restrict__ bias_t,
                        const bf16* __restrict__ fc1_wb, const float* __restrict__ fc1_b,
                        const bf16* __restrict__ fc2_wb, const float* __restrict__ fc2_b,
                        const float* __restrict__ n2w, const float* __restrict__ n2b,
                        float* __restrict__ out) {
  __shared__ __align__(16) unsigned char SM[65536];
  const int tid  = threadIdx.x;
  const int wv   = tid >> 6;
  const int lane = tid & 63;
  const int lm   = lane & 15;
  const int lg   = lane >> 4;
  const int lk   = lg << 3;
  const int blk  = blockIdx.x;
  const int b    = blk >> 6;
  const int win  = blk & 63;
  const int wy   = win >> 3, wx = win & 7;
  const int h    = wv;
  const int SB   = 32768 + wv*4096;   // wave-private 4KB bounce strip
  const int LNB  = 32768;             // LN stats overlay (strips / HS region)
  const int HS   = 32768;             // MLP h-chunk buffer

  // ---- stage shifted-window x tile -> bf16 LDS [64][256] XOR-swizzled (XA = 0..32K)
  {
    const int t = tid >> 3, q8 = tid & 7;
    const int iy = t >> 3, ix = t & 7;
    const int gh = (wy*8 + iy + 4) & 63, gw = (wx*8 + ix + 4) & 63;
    const float* src = x + (size_t)(b*4096 + gh*64 + gw) * 256 + q8*32;
#pragma unroll
    for (int i = 0; i < 4; ++i) {
      f32x4 f0 = ld4(src + i*8);
      f32x4 f1 = ld4(src + i*8 + 4);
      *(bf16x8*)(SM + ((t*512 + (q8*32 + i*8)*2) ^ ((t&7)<<4))) = cvt8(f0, f1);
    }
  }
  __syncthreads();   // B0

  bf16x8 qf[4], kf[4], vb[2][2];

  // ---- QKV pass0: q + k (d 0..32) for this head
  {
    const int jq[4] = { h*32 + lm, h*32 + 16 + lm, 256 + h*32 + lm, 256 + h*32 + 16 + lm };
    f32x4 acc[4][4] = {};
#pragma unroll
    for (int kk = 0; kk < 8; ++kk) {
      const int ko = kk*32 + lk;
      bf16x8 a[4], bb[4];
#pragma unroll
      for (int m = 0; m < 4; ++m) {
        const int t = m*16 + lm;
        a[m] = *(const bf16x8*)(SM + ((t*512 + ko*2) ^ ((t&7)<<4)));
      }
#pragma unroll
      for (int n = 0; n < 4; ++n)
        bb[n] = *(const bf16x8*)(qkv_wb + jq[n]*256 + ko);
#pragma unroll
      for (int m = 0; m < 4; ++m)
#pragma unroll
        for (int n = 0; n < 4; ++n)
          acc[m][n] = MFMA16(a[m], bb[n], acc[m][n]);
    }
    float bj[4];
#pragma unroll
    for (int n = 0; n < 4; ++n) bj[n] = qkv_b[jq[n]];
#pragma unroll
    for (int m = 0; m < 4; ++m)
#pragma unroll
      for (int n = 0; n < 4; ++n)
#pragma unroll
        for (int r = 0; r < 4; ++r) acc[m][n][r] += bj[n];
    const float nqw0 = nq_w[lm], nqw1 = nq_w[16+lm];
    const float nkw0 = nk_w[lm], nkw1 = nk_w[16+lm];
#pragma unroll
    for (int m = 0; m < 4; ++m)
#pragma unroll
      for (int r = 0; r < 4; ++r) {
        float q0 = acc[m][0][r], q1 = acc[m][1][r];
        float k0 = acc[m][2][r], k1 = acc[m][3][r];
        float sq = q0*q0 + q1*q1, sk = k0*k0 + k1*k1;
        sq += __shfl_xor(sq, 1); sk += __shfl_xor(sk, 1);
        sq += __shfl_xor(sq, 2); sk += __shfl_xor(sk, 2);
        sq += __shfl_xor(sq, 4); sk += __shfl_xor(sk, 4);
        sq += __shfl_xor(sq, 8); sk += __shfl_xor(sk, 8);
        const float scq = rsqrtf(sq * (1.0f/32.0f) + 1.1920929e-07f);
        const float sck = rsqrtf(sk * (1.0f/32.0f) + 1.1920929e-07f);
        acc[m][0][r] = q0*scq*nqw0; acc[m][1][r] = q1*scq*nqw1;
        acc[m][2][r] = k0*sck*nkw0; acc[m][3][r] = k1*sck*nkw1;
      }
#pragma unroll
    for (int m = 0; m < 4; ++m)
#pragma unroll
      for (int n = 0; n < 2; ++n)
#pragma unroll
        for (int r = 0; r < 4; ++r)
          *(bf16*)(SM + SB + m*1024 + (lg*4+r)*16 + (n*2 + (lm>>3))*256 + (lm&7)*2)
            = (bf16)acc[m][n][r];
    FENCE();
#pragma unroll
    for (int m = 0; m < 4; ++m)
      qf[m] = *(const bf16x8*)(SM + SB + m*1024 + lane*16);
    FENCE();
#pragma unroll
    for (int m = 0; m < 4; ++m)
#pragma unroll
      for (int n = 0; n < 2; ++n)
#pragma unroll
        for (int r = 0; r < 4; ++r)
          *(bf16*)(SM + SB + m*1024 + (lg*4+r)*16 + (n*2 + (lm>>3))*256 + (lm&7)*2)
            = (bf16)acc[m][2+n][r];
    FENCE();
#pragma unroll
    for (int m = 0; m < 4; ++m)
      kf[m] = *(const bf16x8*)(SM + SB + m*1024 + lane*16);
    FENCE();
  }

  // ---- QKV pass1: v for this head
  {
    const int jv[2] = { 512 + h*32 + lm, 512 + h*32 + 16 + lm };
    f32x4 vacc[4][2] = {};
#pragma unroll
    for (int kk = 0; kk < 8; ++kk) {
      const int ko = kk*32 + lk;
      bf16x8 a[4], bb[2];
#pragma unroll
      for (int m = 0; m < 4; ++m) {
        const int t = m*16 + lm;
        a[m] = *(const bf16x8*)(SM + ((t*512 + ko*2) ^ ((t&7)<<4)));
      }
#pragma unroll
      for (int n = 0; n < 2; ++n)
        bb[n] = *(const bf16x8*)(qkv_wb + jv[n]*256 + ko);
#pragma unroll
      for (int m = 0; m < 4; ++m)
#pragma unroll
        for (int n = 0; n < 2; ++n)
          vacc[m][n] = MFMA16(a[m], bb[n], vacc[m][n]);
    }
    float bj[2] = { qkv_b[jv[0]], qkv_b[jv[1]] };
#pragma unroll
    for (int m = 0; m < 4; ++m)
#pragma unroll
      for (int n = 0; n < 2; ++n)
#pragma unroll
        for (int r = 0; r < 4; ++r)
          *(bf16*)(SM + SB + (n*2 + (m>>1))*1024 + lm*16
                   + ((m&1)*2 + ((lg*4+r)>>3))*256 + ((lg*4+r)&7)*2)
            = (bf16)(vacc[m][n][r] + bj[n]);
    FENCE();
#pragma unroll
    for (int nf = 0; nf < 2; ++nf)
#pragma unroll
      for (int ks = 0; ks < 2; ++ks)
        vb[nf][ks] = *(const bf16x8*)(SM + SB + (nf*2+ks)*1024 + lane*16);
    FENCE();
  }
  __syncthreads();   // B1

  // ---- QK^T + bias + mask + softmax
  f32x4 s[4][4];
#pragma unroll
  for (int m = 0; m < 4; ++m)
#pragma unroll
    for (int n = 0; n < 4; ++n) {
      f32x4 z = {};
      s[m][n] = MFMA16(qf[m], kf[n], z);
    }
#pragma unroll
  for (int n = 0; n < 4; ++n) {
    const int ct = n*16 + lm;
    const int idc = ((wy==7) ? (((ct>>3) < 4) ? 1 : 2) : 0) * 3
                  + ((wx==7) ? (((ct&7)  < 4) ? 1 : 2) : 0);
#pragma unroll
    for (int m = 0; m < 4; ++m) {
      const f32x4 bt = *(const f32x4*)(bias_t + h*4096 + ct*64 + m*16 + lg*4);
#pragma unroll
      for (int r = 0; r < 4; ++r) {
        const int rt = m*16 + lg*4 + r;
        const int idr = ((wy==7) ? (((rt>>3) < 4) ? 1 : 2) : 0) * 3
                      + ((wx==7) ? (((rt&7)  < 4) ? 1 : 2) : 0);
        float add = bt[r];
        if (idr != idc) add -= 100.0f;
        s[m][n][r] += add;
      }
    }
  }
#pragma unroll
  for (int m = 0; m < 4; ++m)
#pragma unroll
    for (int r = 0; r < 4; ++r) {
      float v0 = s[m][0][r], v1 = s[m][1][r], v2 = s[m][2][r], v3 = s[m][3][r];
      float mx = fmaxf(fmaxf(v0, v1), fmaxf(v2, v3));
      mx = fmaxf(mx, __shfl_xor(mx, 1));
      mx = fmaxf(mx, __shfl_xor(mx, 2));
      mx = fmaxf(mx, __shfl_xor(mx, 4));
      mx = fmaxf(mx, __shfl_xor(mx, 8));
      v0 = __expf(v0 - mx); v1 = __expf(v1 - mx);
      v2 = __expf(v2 - mx); v3 = __expf(v3 - mx);
      float sm = v0 + v1 + v2 + v3;
      sm += __shfl_xor(sm, 1);
      sm += __shfl_xor(sm, 2);
      sm += __shfl_xor(sm, 4);
      sm += __shfl_xor(sm, 8);
      const float inv = 1.0f / sm;
      s[m][0][r] = v0*inv; s[m][1][r] = v1*inv; s[m][2][r] = v2*inv; s[m][3][r] = v3*inv;
    }

  // ---- PV through strip in two 32-row halves
  f32x4 yacc[4][2] = {};
#pragma unroll
  for (int mh = 0; mh < 2; ++mh) {
#pragma unroll
    for (int ml = 0; ml < 2; ++ml)
#pragma unroll
      for (int n = 0; n < 4; ++n)
#pragma unroll
        for (int r = 0; r < 4; ++r)
          *(bf16*)(SM + SB + (ml*2 + (n>>1))*1024 + (lg*4+r)*16
                   + ((n&1)*2 + (lm>>3))*256 + (lm&7)*2)
            = (bf16)s[mh*2+ml][n][r];
    FENCE();
    bf16x8 pa[2][2];
#pragma unroll
    for (int ml = 0; ml < 2; ++ml)
#pragma unroll
      for (int ks = 0; ks < 2; ++ks)
        pa[ml][ks] = *(const bf16x8*)(SM + SB + (ml*2+ks)*1024 + lane*16);
    FENCE();
#pragma unroll
    for (int ml = 0; ml < 2; ++ml)
#pragma unroll
      for (int ks = 0; ks < 2; ++ks)
#pragma unroll
        for (int nf = 0; nf < 2; ++nf)
          yacc[mh*2+ml][nf] = MFMA16(pa[ml][ks], vb[nf][ks], yacc[mh*2+ml][nf]);
  }

  // ---- y (head h) -> y_all in XA area
#pragma unroll
  for (int m = 0; m < 4; ++m)
#pragma unroll
    for (int nf = 0; nf < 2; ++nf)
#pragma unroll
      for (int r = 0; r < 4; ++r) {
        const int t = m*16 + lg*4 + r;
        const int c = h*32 + nf*16 + lm;
        *(bf16*)(SM + ((t*512 + c*2) ^ ((t&7)<<4))) = (bf16)yacc[m][nf][r];
      }
  __syncthreads();   // B2

  // ---- prefetch x residual (consumed after B4) -- covered by proj + LN1 stats
  float xr0[4][4], xr1[4][4];
#pragma unroll
  for (int m = 0; m < 4; ++m)
#pragma unroll
    for (int r = 0; r < 4; ++r) {
      const int row = m*16 + lg*4 + r;
      const int iy = row >> 3, ix = row & 7;
      const int gh = (wy*8 + iy + 4) & 63, gw = (wx*8 + ix + 4) & 63;
      const size_t gp = (size_t)(b*4096 + gh*64 + gw) * 256 + wv*32 + lm;
      xr0[m][r] = x[gp];
      xr1[m][r] = x[gp + 16];
    }

  // ---- proj: wave covers 32 cols, K=256
  f32x4 pacc[4][2] = {};
#pragma unroll
  for (int kk = 0; kk < 8; ++kk) {
    const int ko = kk*32 + lk;
    bf16x8 a[4], bb[2];
#pragma unroll
    for (int m = 0; m < 4; ++m) {
      const int t = m*16 + lm;
      a[m] = *(const bf16x8*)(SM + ((t*512 + ko*2) ^ ((t&7)<<4)));
    }
#pragma unroll
    for (int n = 0; n < 2; ++n) {
      const int j = wv*32 + n*16 + lm;
      bb[n] = *(const bf16x8*)(proj_wb + j*256 + ko);
    }
#pragma unroll
    for (int m = 0; m < 4; ++m)
#pragma unroll
      for (int n = 0; n < 2; ++n)
        pacc[m][n] = MFMA16(a[m], bb[n], pacc[m][n]);
  }
  {
    const float b0 = proj_b[wv*32 + lm], b1 = proj_b[wv*32 + 16 + lm];
#pragma unroll
    for (int m = 0; m < 4; ++m)
#pragma unroll
      for (int r = 0; r < 4; ++r) { pacc[m][0][r] += b0; pacc[m][1][r] += b1; }
  }

  // ---- LN1 stats (fragment reduce)
#pragma unroll
  for (int m = 0; m < 4; ++m)
#pragma unroll
    for (int r = 0; r < 4; ++r) {
      float p  = pacc[m][0][r] + pacc[m][1][r];
      float ps = pacc[m][0][r]*pacc[m][0][r] + pacc[m][1][r]*pacc[m][1][r];
      p  += __shfl_xor(p, 1);  ps += __shfl_xor(ps, 1);
      p  += __shfl_xor(p, 2);  ps += __shfl_xor(ps, 2);
      p  += __shfl_xor(p, 4);  ps += __shfl_xor(ps, 4);
      p  += __shfl_xor(p, 8);  ps += __shfl_xor(ps, 8);
      if (lm == 0) {
        const int row = m*16 + lg*4 + r;
        *(float*)(SM + LNB + row*32 + wv*4) = p;
        *(float*)(SM + LNB + 2048 + row*32 + wv*4) = ps;
      }
    }
  __syncthreads();   // B3
  if (tid < 64) {
    const int row = tid;
    f32x4 s0 = *(const f32x4*)(SM + LNB + row*32);
    f32x4 s1 = *(const f32x4*)(SM + LNB + row*32 + 16);
    f32x4 q0 = *(const f32x4*)(SM + LNB + 2048 + row*32);
    f32x4 q1 = *(const f32x4*)(SM + LNB + 2048 + row*32 + 16);
    const float sm_ = s0[0]+s0[1]+s0[2]+s0[3]+s1[0]+s1[1]+s1[2]+s1[3];
    const float qq  = q0[0]+q0[1]+q0[2]+q0[3]+q1[0]+q1[1]+q1[2]+q1[3];
    const float mu  = sm_ * (1.0f/256.0f);
    const float var = qq * (1.0f/256.0f) - mu*mu;
    float2 mi; mi.x = mu; mi.y = rsqrtf(var + 1e-5f);
    *(float2*)(SM + LNB + 4096 + row*8) = mi;
  }
  __syncthreads();   // B4

  // ---- LN1 apply + x shortcut (prefetched), x1 stays in pacc; bf16 copy -> XA
  {
    const float w0 = n1w[wv*32 + lm],  w1 = n1w[wv*32 + 16 + lm];
    const float b0 = n1b[wv*32 + lm],  b1 = n1b[wv*32 + 16 + lm];
#pragma unroll
    for (int m = 0; m < 4; ++m)
#pragma unroll
      for (int r = 0; r < 4; ++r) {
        const int row = m*16 + lg*4 + r;
        const float2 mi = *(const float2*)(SM + LNB + 4096 + row*8);
        pacc[m][0][r] = (pacc[m][0][r] - mi.x)*mi.y*w0 + b0 + xr0[m][r];
        pacc[m][1][r] = (pacc[m][1][r] - mi.x)*mi.y*w1 + b1 + xr1[m][r];
      }
  }
  __syncthreads();   // B5: stats read done; XA (y_all) dead -> overwrite with x1 bf16
#pragma unroll
  for (int m = 0; m < 4; ++m)
#pragma unroll
    for (int r = 0; r < 4; ++r) {
      const int t = m*16 + lg*4 + r;
      const int c0 = wv*32 + lm, c1 = wv*32 + 16 + lm;
      *(bf16*)(SM + ((t*512 + c0*2) ^ ((t&7)<<4))) = (bf16)pacc[m][0][r];
      *(bf16*)(SM + ((t*512 + c1*2) ^ ((t&7)<<4))) = (bf16)pacc[m][1][r];
    }
  __syncthreads();   // B6: XA = x1 bf16 ready; HS region free

  // ================= MLP phase (same 64 tokens, in-block) =================
  f32x4 acc2[4][2] = {};
#pragma unroll 1
  for (int kc = 0; kc < 4; ++kc) {
    f32x4 acc1[4][2] = {};
#pragma unroll
    for (int kk = 0; kk < 8; ++kk) {
      const int ko = kk*32 + lk;
      bf16x8 a[4], bb[2];
#pragma unroll
      for (int m = 0; m < 4; ++m) {
        const int t = m*16 + lm;
        a[m] = *(const bf16x8*)(SM + ((t*512 + ko*2) ^ ((t&7)<<4)));
      }
#pragma unroll
      for (int n = 0; n < 2; ++n) {
        const int j = kc*256 + wv*32 + n*16 + lm;
        bb[n] = *(const bf16x8*)(fc1_wb + j*256 + ko);
      }
#pragma unroll
      for (int m = 0; m < 4; ++m)
#pragma unroll
        for (int n = 0; n < 2; ++n)
          acc1[m][n] = MFMA16(a[m], bb[n], acc1[m][n]);
    }
    // fast GELU + bias -> HS
#pragma unroll
    for (int n = 0; n < 2; ++n) {
      const float bj = fc1_b[kc*256 + wv*32 + n*16 + lm];
      const int cb = wv*64 + n*32 + lm*2;
#pragma unroll
      for (int m = 0; m < 4; ++m)
#pragma unroll
        for (int r = 0; r < 4; ++r) {
          const int t = m*16 + lg*4 + r;
          const float v = gelu_fast(acc1[m][n][r] + bj);
          *(bf16*)(SM + HS + ((t*512 + cb) ^ ((t&7)<<4))) = (bf16)v;
        }
    }
    __syncthreads();
    // fc2 partial
#pragma unroll
    for (int kk = 0; kk < 8; ++kk) {
      const int ko = kk*32 + lk;
      bf16x8 a[4], bb[2];
#pragma unroll
      for (int m = 0; m < 4; ++m) {
        const int t = m*16 + lm;
        a[m] = *(const bf16x8*)(SM + HS + ((t*512 + ko*2) ^ ((t&7)<<4)));
      }
#pragma unroll
      for (int n = 0; n < 2; ++n) {
        const int j = wv*32 + n*16 + lm;
        bb[n] = *(const bf16x8*)(fc2_wb + (size_t)j*1024 + kc*256 + ko);
      }
#pragma unroll
      for (int m = 0; m < 4; ++m)
#pragma unroll
        for (int n = 0; n < 2; ++n)
          acc2[m][n] = MFMA16(a[m], bb[n], acc2[m][n]);
    }
    __syncthreads();
  }

  // fc2 bias
  {
    const float b0 = fc2_b[wv*32 + lm], b1 = fc2_b[wv*32 + 16 + lm];
#pragma unroll
    for (int m = 0; m < 4; ++m)
#pragma unroll
      for (int r = 0; r < 4; ++r) { acc2[m][0][r] += b0; acc2[m][1][r] += b1; }
  }

  // ---- LN2 stats
#pragma unroll
  for (int m = 0; m < 4; ++m)
#pragma unroll
    for (int r = 0; r < 4; ++r) {
      float p  = acc2[m][0][r] + acc2[m][1][r];
      float ps = acc2[m][0][r]*acc2[m][0][r] + acc2[m][1][r]*acc2[m][1][r];
      p  += __shfl_xor(p, 1);  ps += __shfl_xor(ps, 1);
      p  += __shfl_xor(p, 2);  ps += __shfl_xor(ps, 2);
      p  += __shfl_xor(p, 4);  ps += __shfl_xor(ps, 4);
      p  += __shfl_xor(p, 8);  ps += __shfl_xor(ps, 8);
      if (lm == 0) {
        const int row = m*16 + lg*4 + r;
        *(float*)(SM + LNB + row*32 + wv*4) = p;
        *(float*)(SM + LNB + 2048 + row*32 + wv*4) = ps;
      }
    }
  __syncthreads();
  if (tid < 64) {
    const int row = tid;
    f32x4 s0 = *(const f32x4*)(SM + LNB + row*32);
    f32x4 s1 = *(const f32x4*)(SM + LNB + row*32 + 16);
    f32x4 q0 = *(const f32x4*)(SM + LNB + 2048 + row*32);
    f32x4 q1 = *(const f32x4*)(SM + LNB + 2048 + row*32 + 16);
    const float sm_ = s0[0]+s0[1]+s0[2]+s0[3]+s1[0]+s1[1]+s1[2]+s1[3];
    const float qq  = q0[0]+q0[1]+q0[2]+q0[3]+q1[0]+q1[1]+q1[2]+q1[3];
    const float mu  = sm_ * (1.0f/256.0f);
    const float var = qq * (1.0f/256.0f) - mu*mu;
    float2 mi; mi.x = mu; mi.y = rsqrtf(var + 1e-5f);
    *(float2*)(SM + LNB + 4096 + row*8) = mi;
  }
  __syncthreads();

  // cache LN2 stats in regs (Y2 overlay will clobber all LDS)
  float2 mi2[4][4];
#pragma unroll
  for (int m = 0; m < 4; ++m)
#pragma unroll
    for (int r = 0; r < 4; ++r)
      mi2[m][r] = *(const float2*)(SM + LNB + 4096 + (m*16 + lg*4 + r)*8);
  __syncthreads();   // all LDS dead

  // ---- out_frag = x1(regs) + LN2(acc2) -> Y2 fp32 [64][256] 2-key XOR swizzle
  {
    const float w0 = n2w[wv*32 + lm],  w1 = n2w[wv*32 + 16 + lm];
    const float b0 = n2b[wv*32 + lm],  b1 = n2b[wv*32 + 16 + lm];
#pragma unroll
    for (int m = 0; m < 4; ++m)
#pragma unroll
      for (int r = 0; r < 4; ++r) {
        const int t = m*16 + lg*4 + r;
        const int j0 = wv*32 + lm, j1 = wv*32 + 16 + lm;
        *(float*)(SM + t*1024 + ((j0*4) ^ (((t&7) ^ ((j0>>5)&7))<<4)))
          = (acc2[m][0][r] - mi2[m][r].x)*mi2[m][r].y*w0 + b0 + pacc[m][0][r];
        *(float*)(SM + t*1024 + ((j1*4) ^ (((t&7) ^ ((j1>>5)&7))<<4)))
          = (acc2[m][1][r] - mi2[m][r].x)*mi2[m][r].y*w1 + b1 + pacc[m][1][r];
      }
  }
  __syncthreads();

  // ---- epilogue: thread owns 128B run of a row -> store at unshifted position
  {
    const int t8 = tid >> 3, sub = tid & 7;
    const int key = ((t8&7) ^ sub) << 4;
    const int iy = t8 >> 3, ix = t8 & 7;
    const int gh = (wy*8 + iy + 4) & 63, gw = (wx*8 + ix + 4) & 63;
    const size_t grow = (size_t)(b*4096 + gh*64 + gw) * 256;
#pragma unroll
    for (int i = 0; i < 8; ++i) {
      const int c = sub*32 + i*4;
      f32x4 t4 = *(const f32x4*)(SM + t8*1024 + ((c*4) ^ key));
      *(f32x4*)(out + grow + c) = t4;
    }
  }
}

extern "C" void kernel_launch(void* const* d_in, const int* in_sizes, int n_in,
                              void* d_out, int out_size, void* d_ws, size_t ws_size,
                              hipStream_t stream) {
  const float* x      = (const float*)d_in[0];
  const float* qkv_w  = (const float*)d_in[1];
  const float* qkv_b  = (const float*)d_in[2];
  const float* nq_w   = (const float*)d_in[3];
  const float* nk_w   = (const float*)d_in[4];
  const float* cpb_w1 = (const float*)d_in[5];
  const float* cpb_b1 = (const float*)d_in[6];
  const float* cpb_w2 = (const float*)d_in[7];
  const float* proj_w = (const float*)d_in[8];
  const float* proj_b = (const float*)d_in[9];
  const float* n1w    = (const float*)d_in[10];
  const float* n1b    = (const float*)d_in[11];
  const float* fc1_w  = (const float*)d_in[12];
  const float* fc1_b  = (const float*)d_in[13];
  const float* fc2_w  = (const float*)d_in[14];
  const float* fc2_b  = (const float*)d_in[15];
  const float* n2w    = (const float*)d_in[16];
  const float* n2b    = (const float*)d_in[17];

  char* ws = (char*)d_ws;
  bf16*  qkv_wb  = (bf16*) (ws);                   //   393216 B
  bf16*  proj_wb = (bf16*) (ws + 393216);          //   131072 B
  bf16*  fc1_wb  = (bf16*) (ws + 524288);          //   524288 B
  bf16*  fc2_wb  = (bf16*) (ws + 1048576);         //   524288 B
  float* bias_t  = (float*)(ws + 1572864);         //   131072 B
  float* tab_g   = (float*)(ws + 1703936);         //     7200 B

  prep_weights<<<1024, 256, 0, stream>>>(qkv_w, proj_w, fc1_w, fc2_w,
                                         qkv_wb, proj_wb, fc1_wb, fc2_wb);
  prep_tab<<<225, 64, 0, stream>>>(cpb_w1, cpb_b1, cpb_w2, tab_g);
  prep_expand<<<128, 256, 0, stream>>>(tab_g, bias_t);
  k_fused<<<512, 512, 0, stream>>>(x, qkv_wb, qkv_b, nq_w, nk_w,
                                   proj_wb, proj_b, n1w, n1b, bias_t,
                                   fc1_wb, fc1_b, fc2_wb, fc2_b, n2w, n2b,
                                   (float*)d_out);
}

// Round 19
// 180.872 us; speedup vs baseline: 1.0369x; 1.0166x over previous
//
#include <hip/hip_runtime.h>
#include <hip/hip_bf16.h>
#include <math.h>

typedef __bf16 bf16;
typedef bf16  bf16x8 __attribute__((ext_vector_type(8)));
typedef float f32x4  __attribute__((ext_vector_type(4)));

#define MFMA16(a,b,c) __builtin_amdgcn_mfma_f32_16x16x32_bf16(a,b,c,0,0,0)
#define FENCE() do { asm volatile("s_waitcnt lgkmcnt(0)" ::: "memory"); __builtin_amdgcn_sched_barrier(0); } while(0)

__device__ __forceinline__ f32x4 ld4(const float* p) { return *(const f32x4*)p; }

__device__ __forceinline__ bf16x8 cvt8(const f32x4& a, const f32x4& b) {
  bf16x8 v;
  v[0]=(bf16)a[0]; v[1]=(bf16)a[1]; v[2]=(bf16)a[2]; v[3]=(bf16)a[3];
  v[4]=(bf16)b[0]; v[5]=(bf16)b[1]; v[6]=(bf16)b[2]; v[7]=(bf16)b[3];
  return v;
}

// fast GELU (tanh form via HW exp)
__device__ __forceinline__ float gelu_fast(float x) {
  const float z = 1.5957691216f * (x + 0.044715f * x * x * x);
  return x / (1.0f + __expf(-z));
}

// ---------------- prep: fp32 weights -> bf16 ----------------
__global__ void prep_weights(const float* __restrict__ qkv_w, const float* __restrict__ proj_w,
                             const float* __restrict__ fc1_w, const float* __restrict__ fc2_w,
                             bf16* __restrict__ qkv_wb, bf16* __restrict__ proj_wb,
                             bf16* __restrict__ fc1_wb, bf16* __restrict__ fc2_wb) {
  int i = blockIdx.x * 256 + threadIdx.x;
  if (i < 196608) qkv_wb[i] = (bf16)qkv_w[i];
  if (i <  65536) proj_wb[i] = (bf16)proj_w[i];
  if (i < 262144) { fc1_wb[i] = (bf16)fc1_w[i]; fc2_wb[i] = (bf16)fc2_w[i]; }
}

// ---------------- prep: CPB MLP -> tab[225][8] ----------------
__global__ void prep_tab(const float* __restrict__ w1, const float* __restrict__ b1,
                         const float* __restrict__ w2, float* __restrict__ tab_g) {
  const int c = blockIdx.x;
  const int a = c / 15, bq = c % 15;
  const float g0 = (float)(a - 7) * (8.0f / 7.0f);
  const float g1 = (float)(bq - 7) * (8.0f / 7.0f);
  const float t0 = copysignf(log2f(fabsf(g0) + 1.0f) * (1.0f/3.0f), g0);
  const float t1 = copysignf(log2f(fabsf(g1) + 1.0f) * (1.0f/3.0f), g1);
  const int lane = threadIdx.x;
  float acc[8] = {0.f,0.f,0.f,0.f,0.f,0.f,0.f,0.f};
#pragma unroll
  for (int e = 0; e < 8; ++e) {
    const int h = lane*8 + e;
    float hv = t0 * w1[h*3 + 0] + t1 * w1[h*3 + 1] + b1[h];
    hv = fmaxf(hv, 0.0f);
#pragma unroll
    for (int j = 0; j < 8; ++j) acc[j] += hv * w2[j*512 + h];
  }
#pragma unroll
  for (int j = 0; j < 8; ++j) {
    acc[j] += __shfl_xor(acc[j], 1);
    acc[j] += __shfl_xor(acc[j], 2);
    acc[j] += __shfl_xor(acc[j], 4);
    acc[j] += __shfl_xor(acc[j], 8);
    acc[j] += __shfl_xor(acc[j], 16);
    acc[j] += __shfl_xor(acc[j], 32);
  }
  if (lane == 0) {
#pragma unroll
    for (int j = 0; j < 8; ++j) tab_g[c*8 + j] = acc[j];
  }
}

// ---------------- prep: expand tab -> bias_t[8][ct=64][rt=64] (TRANSPOSED) ----------------
__global__ void prep_expand(const float* __restrict__ tab_g, float* __restrict__ bias_t) {
  const int idx = blockIdx.x * 256 + threadIdx.x;
  const int head = idx >> 12, ct = (idx >> 6) & 63, rt = idx & 63;
  const int dy = (rt >> 3) - (ct >> 3), dx = (rt & 7) - (ct & 7);
  const float v = tab_g[((dy + 7)*15 + (dx + 7))*8 + head];
  bias_t[idx] = 16.0f / (1.0f + __expf(-v));
}

// ---------------- FULLY FUSED Swin block ----------------
// one block per (batch, window); 8 waves; wave = head. LDS 64KB (2 blocks/CU).
// launch_bounds min-BLOCKS=2 -> 128-VGPR budget.
__launch_bounds__(512, 2)
__global__ void k_fused(const float* __restrict__ x,
                        const bf16* __restrict__ qkv_wb, const float* __restrict__ qkv_b,
                        const float* __restrict__ nq_w, const float* __restrict__ nk_w,
                        const bf16* __restrict__ proj_wb, const float* __restrict__ proj_b,
                        const float* __restrict__ n1w, const float* __restrict__ n1b,
                        const float* __restrict__ bias_t,
                        const bf16* __restrict__ fc1_wb, const float* __restrict__ fc1_b,
                        const bf16* __restrict__ fc2_wb, const float* __restrict__ fc2_b,
                        const float* __restrict__ n2w, const float* __restrict__ n2b,
                        float* __restrict__ out) {
  __shared__ __align__(16) unsigned char SM[65536];
  const int tid  = threadIdx.x;
  const int wv   = tid >> 6;
  const int lane = tid & 63;
  const int lm   = lane & 15;
  const int lg   = lane >> 4;
  const int lk   = lg << 3;
  const int blk  = blockIdx.x;
  const int b    = blk >> 6;
  const int win  = blk & 63;
  const int wy   = win >> 3, wx = win & 7;
  const int h    = wv;
  const int SB   = 32768 + wv*4096;   // wave-private 4KB bounce strip
  const int LNB  = 32768;             // LN stats overlay (strips / HS region)
  const int HS   = 32768;             // MLP h-chunk buffer

  // ---- stage shifted-window x tile -> bf16 LDS [64][256] XOR-swizzled (XA = 0..32K)
  {
    const int t = tid >> 3, q8 = tid & 7;
    const int iy = t >> 3, ix = t & 7;
    const int gh = (wy*8 + iy + 4) & 63, gw = (wx*8 + ix + 4) & 63;
    const float* src = x + (size_t)(b*4096 + gh*64 + gw) * 256 + q8*32;
#pragma unroll
    for (int i = 0; i < 4; ++i) {
      f32x4 f0 = ld4(src + i*8);
      f32x4 f1 = ld4(src + i*8 + 4);
      *(bf16x8*)(SM + ((t*512 + (q8*32 + i*8)*2) ^ ((t&7)<<4))) = cvt8(f0, f1);
    }
  }
  __syncthreads();   // B0

  bf16x8 qf[4], kf[4], vb[2][2];

  // ---- QKV pass0: q + k (d 0..32) for this head
  {
    const int jq[4] = { h*32 + lm, h*32 + 16 + lm, 256 + h*32 + lm, 256 + h*32 + 16 + lm };
    f32x4 acc[4][4] = {};
#pragma unroll
    for (int kk = 0; kk < 8; ++kk) {
      const int ko = kk*32 + lk;
      bf16x8 a[4], bb[4];
#pragma unroll
      for (int m = 0; m < 4; ++m) {
        const int t = m*16 + lm;
        a[m] = *(const bf16x8*)(SM + ((t*512 + ko*2) ^ ((t&7)<<4)));
      }
#pragma unroll
      for (int n = 0; n < 4; ++n)
        bb[n] = *(const bf16x8*)(qkv_wb + jq[n]*256 + ko);
#pragma unroll
      for (int m = 0; m < 4; ++m)
#pragma unroll
        for (int n = 0; n < 4; ++n)
          acc[m][n] = MFMA16(a[m], bb[n], acc[m][n]);
    }
    float bj[4];
#pragma unroll
    for (int n = 0; n < 4; ++n) bj[n] = qkv_b[jq[n]];
#pragma unroll
    for (int m = 0; m < 4; ++m)
#pragma unroll
      for (int n = 0; n < 4; ++n)
#pragma unroll
        for (int r = 0; r < 4; ++r) acc[m][n][r] += bj[n];
    const float nqw0 = nq_w[lm], nqw1 = nq_w[16+lm];
    const float nkw0 = nk_w[lm], nkw1 = nk_w[16+lm];
#pragma unroll
    for (int m = 0; m < 4; ++m)
#pragma unroll
      for (int r = 0; r < 4; ++r) {
        float q0 = acc[m][0][r], q1 = acc[m][1][r];
        float k0 = acc[m][2][r], k1 = acc[m][3][r];
        float sq = q0*q0 + q1*q1, sk = k0*k0 + k1*k1;
        sq += __shfl_xor(sq, 1); sk += __shfl_xor(sk, 1);
        sq += __shfl_xor(sq, 2); sk += __shfl_xor(sk, 2);
        sq += __shfl_xor(sq, 4); sk += __shfl_xor(sk, 4);
        sq += __shfl_xor(sq, 8); sk += __shfl_xor(sk, 8);
        const float scq = rsqrtf(sq * (1.0f/32.0f) + 1.1920929e-07f);
        const float sck = rsqrtf(sk * (1.0f/32.0f) + 1.1920929e-07f);
        acc[m][0][r] = q0*scq*nqw0; acc[m][1][r] = q1*scq*nqw1;
        acc[m][2][r] = k0*sck*nkw0; acc[m][3][r] = k1*sck*nkw1;
      }
#pragma unroll
    for (int m = 0; m < 4; ++m)
#pragma unroll
      for (int n = 0; n < 2; ++n)
#pragma unroll
        for (int r = 0; r < 4; ++r)
          *(bf16*)(SM + SB + m*1024 + (lg*4+r)*16 + (n*2 + (lm>>3))*256 + (lm&7)*2)
            = (bf16)acc[m][n][r];
    FENCE();
#pragma unroll
    for (int m = 0; m < 4; ++m)
      qf[m] = *(const bf16x8*)(SM + SB + m*1024 + lane*16);
    FENCE();
#pragma unroll
    for (int m = 0; m < 4; ++m)
#pragma unroll
      for (int n = 0; n < 2; ++n)
#pragma unroll
        for (int r = 0; r < 4; ++r)
          *(bf16*)(SM + SB + m*1024 + (lg*4+r)*16 + (n*2 + (lm>>3))*256 + (lm&7)*2)
            = (bf16)acc[m][2+n][r];
    FENCE();
#pragma unroll
    for (int m = 0; m < 4; ++m)
      kf[m] = *(const bf16x8*)(SM + SB + m*1024 + lane*16);
    FENCE();
  }

  // ---- QKV pass1: v for this head
  {
    const int jv[2] = { 512 + h*32 + lm, 512 + h*32 + 16 + lm };
    f32x4 vacc[4][2] = {};
#pragma unroll
    for (int kk = 0; kk < 8; ++kk) {
      const int ko = kk*32 + lk;
      bf16x8 a[4], bb[2];
#pragma unroll
      for (int m = 0; m < 4; ++m) {
        const int t = m*16 + lm;
        a[m] = *(const bf16x8*)(SM + ((t*512 + ko*2) ^ ((t&7)<<4)));
      }
#pragma unroll
      for (int n = 0; n < 2; ++n)
        bb[n] = *(const bf16x8*)(qkv_wb + jv[n]*256 + ko);
#pragma unroll
      for (int m = 0; m < 4; ++m)
#pragma unroll
        for (int n = 0; n < 2; ++n)
          vacc[m][n] = MFMA16(a[m], bb[n], vacc[m][n]);
    }
    float bj[2] = { qkv_b[jv[0]], qkv_b[jv[1]] };
#pragma unroll
    for (int m = 0; m < 4; ++m)
#pragma unroll
      for (int n = 0; n < 2; ++n)
#pragma unroll
        for (int r = 0; r < 4; ++r)
          *(bf16*)(SM + SB + (n*2 + (m>>1))*1024 + lm*16
                   + ((m&1)*2 + ((lg*4+r)>>3))*256 + ((lg*4+r)&7)*2)
            = (bf16)(vacc[m][n][r] + bj[n]);
    FENCE();
#pragma unroll
    for (int nf = 0; nf < 2; ++nf)
#pragma unroll
      for (int ks = 0; ks < 2; ++ks)
        vb[nf][ks] = *(const bf16x8*)(SM + SB + (nf*2+ks)*1024 + lane*16);
    FENCE();
  }
  __syncthreads();   // B1

  // ---- QK^T + bias + mask + softmax (no-max: s <= ||q||*||k|| + 16 <= 48, exp-safe)
  f32x4 s[4][4];
#pragma unroll
  for (int m = 0; m < 4; ++m)
#pragma unroll
    for (int n = 0; n < 4; ++n) {
      f32x4 z = {};
      s[m][n] = MFMA16(qf[m], kf[n], z);
    }
#pragma unroll
  for (int n = 0; n < 4; ++n) {
    const int ct = n*16 + lm;
    const int idc = ((wy==7) ? (((ct>>3) < 4) ? 1 : 2) : 0) * 3
                  + ((wx==7) ? (((ct&7)  < 4) ? 1 : 2) : 0);
#pragma unroll
    for (int m = 0; m < 4; ++m) {
      const f32x4 bt = *(const f32x4*)(bias_t + h*4096 + ct*64 + m*16 + lg*4);
#pragma unroll
      for (int r = 0; r < 4; ++r) {
        const int rt = m*16 + lg*4 + r;
        const int idr = ((wy==7) ? (((rt>>3) < 4) ? 1 : 2) : 0) * 3
                      + ((wx==7) ? (((rt&7)  < 4) ? 1 : 2) : 0);
        float add = bt[r];
        if (idr != idc) add -= 100.0f;
        s[m][n][r] += add;
      }
    }
  }
#pragma unroll
  for (int m = 0; m < 4; ++m)
#pragma unroll
    for (int r = 0; r < 4; ++r) {
      float v0 = __expf(s[m][0][r]), v1 = __expf(s[m][1][r]);
      float v2 = __expf(s[m][2][r]), v3 = __expf(s[m][3][r]);
      float sm = v0 + v1 + v2 + v3;
      sm += __shfl_xor(sm, 1);
      sm += __shfl_xor(sm, 2);
      sm += __shfl_xor(sm, 4);
      sm += __shfl_xor(sm, 8);
      const float inv = 1.0f / sm;
      s[m][0][r] = v0*inv; s[m][1][r] = v1*inv; s[m][2][r] = v2*inv; s[m][3][r] = v3*inv;
    }

  // ---- PV through strip in two 32-row halves
  f32x4 yacc[4][2] = {};
#pragma unroll
  for (int mh = 0; mh < 2; ++mh) {
#pragma unroll
    for (int ml = 0; ml < 2; ++ml)
#pragma unroll
      for (int n = 0; n < 4; ++n)
#pragma unroll
        for (int r = 0; r < 4; ++r)
          *(bf16*)(SM + SB + (ml*2 + (n>>1))*1024 + (lg*4+r)*16
                   + ((n&1)*2 + (lm>>3))*256 + (lm&7)*2)
            = (bf16)s[mh*2+ml][n][r];
    FENCE();
    bf16x8 pa[2][2];
#pragma unroll
    for (int ml = 0; ml < 2; ++ml)
#pragma unroll
      for (int ks = 0; ks < 2; ++ks)
        pa[ml][ks] = *(const bf16x8*)(SM + SB + (ml*2+ks)*1024 + lane*16);
    FENCE();
#pragma unroll
    for (int ml = 0; ml < 2; ++ml)
#pragma unroll
      for (int ks = 0; ks < 2; ++ks)
#pragma unroll
        for (int nf = 0; nf < 2; ++nf)
          yacc[mh*2+ml][nf] = MFMA16(pa[ml][ks], vb[nf][ks], yacc[mh*2+ml][nf]);
  }

  // ---- y (head h) -> y_all in XA area
#pragma unroll
  for (int m = 0; m < 4; ++m)
#pragma unroll
    for (int nf = 0; nf < 2; ++nf)
#pragma unroll
      for (int r = 0; r < 4; ++r) {
        const int t = m*16 + lg*4 + r;
        const int c = h*32 + nf*16 + lm;
        *(bf16*)(SM + ((t*512 + c*2) ^ ((t&7)<<4))) = (bf16)yacc[m][nf][r];
      }
  __syncthreads();   // B2

  // ---- prefetch x residual (consumed after B4) -- covered by proj + LN1 stats
  float xr0[4][4], xr1[4][4];
#pragma unroll
  for (int m = 0; m < 4; ++m)
#pragma unroll
    for (int r = 0; r < 4; ++r) {
      const int row = m*16 + lg*4 + r;
      const int iy = row >> 3, ix = row & 7;
      const int gh = (wy*8 + iy + 4) & 63, gw = (wx*8 + ix + 4) & 63;
      const size_t gp = (size_t)(b*4096 + gh*64 + gw) * 256 + wv*32 + lm;
      xr0[m][r] = x[gp];
      xr1[m][r] = x[gp + 16];
    }

  // ---- proj: wave covers 32 cols, K=256
  f32x4 pacc[4][2] = {};
#pragma unroll
  for (int kk = 0; kk < 8; ++kk) {
    const int ko = kk*32 + lk;
    bf16x8 a[4], bb[2];
#pragma unroll
    for (int m = 0; m < 4; ++m) {
      const int t = m*16 + lm;
      a[m] = *(const bf16x8*)(SM + ((t*512 + ko*2) ^ ((t&7)<<4)));
    }
#pragma unroll
    for (int n = 0; n < 2; ++n) {
      const int j = wv*32 + n*16 + lm;
      bb[n] = *(const bf16x8*)(proj_wb + j*256 + ko);
    }
#pragma unroll
    for (int m = 0; m < 4; ++m)
#pragma unroll
      for (int n = 0; n < 2; ++n)
        pacc[m][n] = MFMA16(a[m], bb[n], pacc[m][n]);
  }
  {
    const float b0 = proj_b[wv*32 + lm], b1 = proj_b[wv*32 + 16 + lm];
#pragma unroll
    for (int m = 0; m < 4; ++m)
#pragma unroll
      for (int r = 0; r < 4; ++r) { pacc[m][0][r] += b0; pacc[m][1][r] += b1; }
  }

  // ---- LN1 stats (fragment reduce)
#pragma unroll
  for (int m = 0; m < 4; ++m)
#pragma unroll
    for (int r = 0; r < 4; ++r) {
      float p  = pacc[m][0][r] + pacc[m][1][r];
      float ps = pacc[m][0][r]*pacc[m][0][r] + pacc[m][1][r]*pacc[m][1][r];
      p  += __shfl_xor(p, 1);  ps += __shfl_xor(ps, 1);
      p  += __shfl_xor(p, 2);  ps += __shfl_xor(ps, 2);
      p  += __shfl_xor(p, 4);  ps += __shfl_xor(ps, 4);
      p  += __shfl_xor(p, 8);  ps += __shfl_xor(ps, 8);
      if (lm == 0) {
        const int row = m*16 + lg*4 + r;
        *(float*)(SM + LNB + row*32 + wv*4) = p;
        *(float*)(SM + LNB + 2048 + row*32 + wv*4) = ps;
      }
    }
  __syncthreads();   // B3
  if (tid < 64) {
    const int row = tid;
    f32x4 s0 = *(const f32x4*)(SM + LNB + row*32);
    f32x4 s1 = *(const f32x4*)(SM + LNB + row*32 + 16);
    f32x4 q0 = *(const f32x4*)(SM + LNB + 2048 + row*32);
    f32x4 q1 = *(const f32x4*)(SM + LNB + 2048 + row*32 + 16);
    const float sm_ = s0[0]+s0[1]+s0[2]+s0[3]+s1[0]+s1[1]+s1[2]+s1[3];
    const float qq  = q0[0]+q0[1]+q0[2]+q0[3]+q1[0]+q1[1]+q1[2]+q1[3];
    const float mu  = sm_ * (1.0f/256.0f);
    const float var = qq * (1.0f/256.0f) - mu*mu;
    float2 mi; mi.x = mu; mi.y = rsqrtf(var + 1e-5f);
    *(float2*)(SM + LNB + 4096 + row*8) = mi;
  }
  __syncthreads();   // B4

  // ---- LN1 apply + x shortcut (prefetched), x1 stays in pacc; bf16 copy -> XA
  {
    const float w0 = n1w[wv*32 + lm],  w1 = n1w[wv*32 + 16 + lm];
    const float b0 = n1b[wv*32 + lm],  b1 = n1b[wv*32 + 16 + lm];
#pragma unroll
    for (int m = 0; m < 4; ++m)
#pragma unroll
      for (int r = 0; r < 4; ++r) {
        const int row = m*16 + lg*4 + r;
        const float2 mi = *(const float2*)(SM + LNB + 4096 + row*8);
        pacc[m][0][r] = (pacc[m][0][r] - mi.x)*mi.y*w0 + b0 + xr0[m][r];
        pacc[m][1][r] = (pacc[m][1][r] - mi.x)*mi.y*w1 + b1 + xr1[m][r];
      }
  }
  __syncthreads();   // B5: stats read done; XA (y_all) dead -> overwrite with x1 bf16
#pragma unroll
  for (int m = 0; m < 4; ++m)
#pragma unroll
    for (int r = 0; r < 4; ++r) {
      const int t = m*16 + lg*4 + r;
      const int c0 = wv*32 + lm, c1 = wv*32 + 16 + lm;
      *(bf16*)(SM + ((t*512 + c0*2) ^ ((t&7)<<4))) = (bf16)pacc[m][0][r];
      *(bf16*)(SM + ((t*512 + c1*2) ^ ((t&7)<<4))) = (bf16)pacc[m][1][r];
    }
  __syncthreads();   // B6: XA = x1 bf16 ready; HS region free

  // ================= MLP phase (same 64 tokens, in-block) =================
  f32x4 acc2[4][2] = {};
#pragma unroll 1
  for (int kc = 0; kc < 4; ++kc) {
    f32x4 acc1[4][2] = {};
#pragma unroll
    for (int kk = 0; kk < 8; ++kk) {
      const int ko = kk*32 + lk;
      bf16x8 a[4], bb[2];
#pragma unroll
      for (int m = 0; m < 4; ++m) {
        const int t = m*16 + lm;
        a[m] = *(const bf16x8*)(SM + ((t*512 + ko*2) ^ ((t&7)<<4)));
      }
#pragma unroll
      for (int n = 0; n < 2; ++n) {
        const int j = kc*256 + wv*32 + n*16 + lm;
        bb[n] = *(const bf16x8*)(fc1_wb + j*256 + ko);
      }
#pragma unroll
      for (int m = 0; m < 4; ++m)
#pragma unroll
        for (int n = 0; n < 2; ++n)
          acc1[m][n] = MFMA16(a[m], bb[n], acc1[m][n]);
    }
    // fast GELU + bias -> HS
#pragma unroll
    for (int n = 0; n < 2; ++n) {
      const float bj = fc1_b[kc*256 + wv*32 + n*16 + lm];
      const int cb = wv*64 + n*32 + lm*2;
#pragma unroll
      for (int m = 0; m < 4; ++m)
#pragma unroll
        for (int r = 0; r < 4; ++r) {
          const int t = m*16 + lg*4 + r;
          const float v = gelu_fast(acc1[m][n][r] + bj);
          *(bf16*)(SM + HS + ((t*512 + cb) ^ ((t&7)<<4))) = (bf16)v;
        }
    }
    __syncthreads();
    // fc2 partial
#pragma unroll
    for (int kk = 0; kk < 8; ++kk) {
      const int ko = kk*32 + lk;
      bf16x8 a[4], bb[2];
#pragma unroll
      for (int m = 0; m < 4; ++m) {
        const int t = m*16 + lm;
        a[m] = *(const bf16x8*)(SM + HS + ((t*512 + ko*2) ^ ((t&7)<<4)));
      }
#pragma unroll
      for (int n = 0; n < 2; ++n) {
        const int j = wv*32 + n*16 + lm;
        bb[n] = *(const bf16x8*)(fc2_wb + (size_t)j*1024 + kc*256 + ko);
      }
#pragma unroll
      for (int m = 0; m < 4; ++m)
#pragma unroll
        for (int n = 0; n < 2; ++n)
          acc2[m][n] = MFMA16(a[m], bb[n], acc2[m][n]);
    }
    __syncthreads();
  }

  // fc2 bias
  {
    const float b0 = fc2_b[wv*32 + lm], b1 = fc2_b[wv*32 + 16 + lm];
#pragma unroll
    for (int m = 0; m < 4; ++m)
#pragma unroll
      for (int r = 0; r < 4; ++r) { acc2[m][0][r] += b0; acc2[m][1][r] += b1; }
  }

  // ---- LN2 stats
#pragma unroll
  for (int m = 0; m < 4; ++m)
#pragma unroll
    for (int r = 0; r < 4; ++r) {
      float p  = acc2[m][0][r] + acc2[m][1][r];
      float ps = acc2[m][0][r]*acc2[m][0][r] + acc2[m][1][r]*acc2[m][1][r];
      p  += __shfl_xor(p, 1);  ps += __shfl_xor(ps, 1);
      p  += __shfl_xor(p, 2);  ps += __shfl_xor(ps, 2);
      p  += __shfl_xor(p, 4);  ps += __shfl_xor(ps, 4);
      p  += __shfl_xor(p, 8);  ps += __shfl_xor(ps, 8);
      if (lm == 0) {
        const int row = m*16 + lg*4 + r;
        *(float*)(SM + LNB + row*32 + wv*4) = p;
        *(float*)(SM + LNB + 2048 + row*32 + wv*4) = ps;
      }
    }
  __syncthreads();
  if (tid < 64) {
    const int row = tid;
    f32x4 s0 = *(const f32x4*)(SM + LNB + row*32);
    f32x4 s1 = *(const f32x4*)(SM + LNB + row*32 + 16);
    f32x4 q0 = *(const f32x4*)(SM + LNB + 2048 + row*32);
    f32x4 q1 = *(const f32x4*)(SM + LNB + 2048 + row*32 + 16);
    const float sm_ = s0[0]+s0[1]+s0[2]+s0[3]+s1[0]+s1[1]+s1[2]+s1[3];
    const float qq  = q0[0]+q0[1]+q0[2]+q0[3]+q1[0]+q1[1]+q1[2]+q1[3];
    const float mu  = sm_ * (1.0f/256.0f);
    const float var = qq * (1.0f/256.0f) - mu*mu;
    float2 mi; mi.x = mu; mi.y = rsqrtf(var + 1e-5f);
    *(float2*)(SM + LNB + 4096 + row*8) = mi;
  }
  __syncthreads();

  // cache LN2 stats in regs (Y2 overlay will clobber all LDS)
  float2 mi2[4][4];
#pragma unroll
  for (int m = 0; m < 4; ++m)
#pragma unroll
    for (int r = 0; r < 4; ++r)
      mi2[m][r] = *(const float2*)(SM + LNB + 4096 + (m*16 + lg*4 + r)*8);
  __syncthreads();   // all LDS dead

  // ---- out_frag = x1(regs) + LN2(acc2) -> Y2 fp32 [64][256] 2-key XOR swizzle
  {
    const float w0 = n2w[wv*32 + lm],  w1 = n2w[wv*32 + 16 + lm];
    const float b0 = n2b[wv*32 + lm],  b1 = n2b[wv*32 + 16 + lm];
#pragma unroll
    for (int m = 0; m < 4; ++m)
#pragma unroll
      for (int r = 0; r < 4; ++r) {
        const int t = m*16 + lg*4 + r;
        const int j0 = wv*32 + lm, j1 = wv*32 + 16 + lm;
        *(float*)(SM + t*1024 + ((j0*4) ^ (((t&7) ^ ((j0>>5)&7))<<4)))
          = (acc2[m][0][r] - mi2[m][r].x)*mi2[m][r].y*w0 + b0 + pacc[m][0][r];
        *(float*)(SM + t*1024 + ((j1*4) ^ (((t&7) ^ ((j1>>5)&7))<<4)))
          = (acc2[m][1][r] - mi2[m][r].x)*mi2[m][r].y*w1 + b1 + pacc[m][1][r];
      }
  }
  __syncthreads();

  // ---- epilogue: thread owns 128B run of a row -> store at unshifted position
  {
    const int t8 = tid >> 3, sub = tid & 7;
    const int key = ((t8&7) ^ sub) << 4;
    const int iy = t8 >> 3, ix = t8 & 7;
    const int gh = (wy*8 + iy + 4) & 63, gw = (wx*8 + ix + 4) & 63;
    const size_t grow = (size_t)(b*4096 + gh*64 + gw) * 256;
#pragma unroll
    for (int i = 0; i < 8; ++i) {
      const int c = sub*32 + i*4;
      f32x4 t4 = *(const f32x4*)(SM + t8*1024 + ((c*4) ^ key));
      *(f32x4*)(out + grow + c) = t4;
    }
  }
}

extern "C" void kernel_launch(void* const* d_in, const int* in_sizes, int n_in,
                              void* d_out, int out_size, void* d_ws, size_t ws_size,
                              hipStream_t stream) {
  const float* x      = (const float*)d_in[0];
  const float* qkv_w  = (const float*)d_in[1];
  const float* qkv_b  = (const float*)d_in[2];
  const float* nq_w   = (const float*)d_in[3];
  const float* nk_w   = (const float*)d_in[4];
  const float* cpb_w1 = (const float*)d_in[5];
  const float* cpb_b1 = (const float*)d_in[6];
  const float* cpb_w2 = (const float*)d_in[7];
  const float* proj_w = (const float*)d_in[8];
  const float* proj_b = (const float*)d_in[9];
  const float* n1w    = (const float*)d_in[10];
  const float* n1b    = (const float*)d_in[11];
  const float* fc1_w  = (const float*)d_in[12];
  const float* fc1_b  = (const float*)d_in[13];
  const float* fc2_w  = (const float*)d_in[14];
  const float* fc2_b  = (const float*)d_in[15];
  const float* n2w    = (const float*)d_in[16];
  const float* n2b    = (const float*)d_in[17];

  char* ws = (char*)d_ws;
  bf16*  qkv_wb  = (bf16*) (ws);                   //   393216 B
  bf16*  proj_wb = (bf16*) (ws + 393216);          //   131072 B
  bf16*  fc1_wb  = (bf16*) (ws + 524288);          //   524288 B
  bf16*  fc2_wb  = (bf16*) (ws + 1048576);         //   524288 B
  float* bias_t  = (float*)(ws + 1572864);         //   131072 B
  float* tab_g   = (float*)(ws + 1703936);         //     7200 B

  prep_weights<<<1024, 256, 0, stream>>>(qkv_w, proj_w, fc1_w, fc2_w,
                                         qkv_wb, proj_wb, fc1_wb, fc2_wb);
  prep_tab<<<225, 64, 0, stream>>>(cpb_w1, cpb_b1, cpb_w2, tab_g);
  prep_expand<<<128, 256, 0, stream>>>(tab_g, bias_t);
  k_fused<<<512, 512, 0, stream>>>(x, qkv_wb, qkv_b, nq_w, nk_w,
                                   proj_wb, proj_b, n1w, n1b, bias_t,
                                   fc1_wb, fc1_b, fc2_wb, fc2_b, n2w, n2b,
                                   (float*)d_out);
}

// Round 20
// 174.479 us; speedup vs baseline: 1.0749x; 1.0366x over previous
//
#include <hip/hip_runtime.h>
#include <hip/hip_bf16.h>
#include <math.h>

typedef __bf16 bf16;
typedef bf16  bf16x8 __attribute__((ext_vector_type(8)));
typedef float f32x4  __attribute__((ext_vector_type(4)));

#define MFMA16(a,b,c) __builtin_amdgcn_mfma_f32_16x16x32_bf16(a,b,c,0,0,0)
#define FENCE() do { asm volatile("s_waitcnt lgkmcnt(0)" ::: "memory"); __builtin_amdgcn_sched_barrier(0); } while(0)

__device__ __forceinline__ f32x4 ld4(const float* p) { return *(const f32x4*)p; }

__device__ __forceinline__ bf16x8 cvt8(const f32x4& a, const f32x4& b) {
  bf16x8 v;
  v[0]=(bf16)a[0]; v[1]=(bf16)a[1]; v[2]=(bf16)a[2]; v[3]=(bf16)a[3];
  v[4]=(bf16)b[0]; v[5]=(bf16)b[1]; v[6]=(bf16)b[2]; v[7]=(bf16)b[3];
  return v;
}

// fast GELU (tanh form via HW exp)
__device__ __forceinline__ float gelu_fast(float x) {
  const float z = 1.5957691216f * (x + 0.044715f * x * x * x);
  return x / (1.0f + __expf(-z));
}

// ---------------- prep: fp32 weights -> bf16 ----------------
__global__ void prep_weights(const float* __restrict__ qkv_w, const float* __restrict__ proj_w,
                             const float* __restrict__ fc1_w, const float* __restrict__ fc2_w,
                             bf16* __restrict__ qkv_wb, bf16* __restrict__ proj_wb,
                             bf16* __restrict__ fc1_wb, bf16* __restrict__ fc2_wb) {
  int i = blockIdx.x * 256 + threadIdx.x;
  if (i < 196608) qkv_wb[i] = (bf16)qkv_w[i];
  if (i <  65536) proj_wb[i] = (bf16)proj_w[i];
  if (i < 262144) { fc1_wb[i] = (bf16)fc1_w[i]; fc2_wb[i] = (bf16)fc2_w[i]; }
}

// ---------------- prep: CPB MLP -> tab[225][8] ----------------
__global__ void prep_tab(const float* __restrict__ w1, const float* __restrict__ b1,
                         const float* __restrict__ w2, float* __restrict__ tab_g) {
  const int c = blockIdx.x;
  const int a = c / 15, bq = c % 15;
  const float g0 = (float)(a - 7) * (8.0f / 7.0f);
  const float g1 = (float)(bq - 7) * (8.0f / 7.0f);
  const float t0 = copysignf(log2f(fabsf(g0) + 1.0f) * (1.0f/3.0f), g0);
  const float t1 = copysignf(log2f(fabsf(g1) + 1.0f) * (1.0f/3.0f), g1);
  const int lane = threadIdx.x;
  float acc[8] = {0.f,0.f,0.f,0.f,0.f,0.f,0.f,0.f};
#pragma unroll
  for (int e = 0; e < 8; ++e) {
    const int h = lane*8 + e;
    float hv = t0 * w1[h*3 + 0] + t1 * w1[h*3 + 1] + b1[h];
    hv = fmaxf(hv, 0.0f);
#pragma unroll
    for (int j = 0; j < 8; ++j) acc[j] += hv * w2[j*512 + h];
  }
#pragma unroll
  for (int j = 0; j < 8; ++j) {
    acc[j] += __shfl_xor(acc[j], 1);
    acc[j] += __shfl_xor(acc[j], 2);
    acc[j] += __shfl_xor(acc[j], 4);
    acc[j] += __shfl_xor(acc[j], 8);
    acc[j] += __shfl_xor(acc[j], 16);
    acc[j] += __shfl_xor(acc[j], 32);
  }
  if (lane == 0) {
#pragma unroll
    for (int j = 0; j < 8; ++j) tab_g[c*8 + j] = acc[j];
  }
}

// ---------------- prep: expand tab -> bias_t[8][ct=64][rt=64] (TRANSPOSED) ----------------
__global__ void prep_expand(const float* __restrict__ tab_g, float* __restrict__ bias_t) {
  const int idx = blockIdx.x * 256 + threadIdx.x;
  const int head = idx >> 12, ct = (idx >> 6) & 63, rt = idx & 63;
  const int dy = (rt >> 3) - (ct >> 3), dx = (rt & 7) - (ct & 7);
  const float v = tab_g[((dy + 7)*15 + (dx + 7))*8 + head];
  bias_t[idx] = 16.0f / (1.0f + __expf(-v));
}

// ---------------- FULLY FUSED Swin block ----------------
// one block per (batch, window); 8 waves; wave = head. LDS 64KB (2 blocks/CU).
// launch_bounds min-BLOCKS=2 -> 128-VGPR budget.
__launch_bounds__(512, 2)
__global__ void k_fused(const float* __restrict__ x,
                        const bf16* __restrict__ qkv_wb, const float* __restrict__ qkv_b,
                        const float* __restrict__ nq_w, const float* __restrict__ nk_w,
                        const bf16* __restrict__ proj_wb, const float* __restrict__ proj_b,
                        const float* __restrict__ n1w, const float* __restrict__ n1b,
                        const float* __restrict__ bias_t,
                        const bf16* __restrict__ fc1_wb, const float* __restrict__ fc1_b,
                        const bf16* __restrict__ fc2_wb, const float* __restrict__ fc2_b,
                        const float* __restrict__ n2w, const float* __restrict__ n2b,
                        float* __restrict__ out) {
  __shared__ __align__(16) unsigned char SM[65536];
  const int tid  = threadIdx.x;
  const int wv   = tid >> 6;
  const int lane = tid & 63;
  const int lm   = lane & 15;
  const int lg   = lane >> 4;
  const int lk   = lg << 3;
  const int blk  = blockIdx.x;
  const int b    = blk >> 6;
  const int win  = blk & 63;
  const int wy   = win >> 3, wx = win & 7;
  const int h    = wv;
  const int SB   = 32768 + wv*4096;   // wave-private 4KB bounce strip
  const int LNB  = 32768;             // LN stats overlay (strips / HS region)
  const int HS   = 32768;             // MLP h-chunk buffer

  // ---- stage shifted-window x tile -> bf16 LDS [64][256] XOR-swizzled (XA = 0..32K)
  {
    const int t = tid >> 3, q8 = tid & 7;
    const int iy = t >> 3, ix = t & 7;
    const int gh = (wy*8 + iy + 4) & 63, gw = (wx*8 + ix + 4) & 63;
    const float* src = x + (size_t)(b*4096 + gh*64 + gw) * 256 + q8*32;
#pragma unroll
    for (int i = 0; i < 4; ++i) {
      f32x4 f0 = ld4(src + i*8);
      f32x4 f1 = ld4(src + i*8 + 4);
      *(bf16x8*)(SM + ((t*512 + (q8*32 + i*8)*2) ^ ((t&7)<<4))) = cvt8(f0, f1);
    }
  }
  __syncthreads();   // B0

  bf16x8 qf[4], kf[4], vb[2][2];

  // ---- QKV pass0: q + k (d 0..32) for this head
  {
    const int jq[4] = { h*32 + lm, h*32 + 16 + lm, 256 + h*32 + lm, 256 + h*32 + 16 + lm };
    f32x4 acc[4][4] = {};
#pragma unroll
    for (int kk = 0; kk < 8; ++kk) {
      const int ko = kk*32 + lk;
      bf16x8 a[4], bb[4];
#pragma unroll
      for (int m = 0; m < 4; ++m) {
        const int t = m*16 + lm;
        a[m] = *(const bf16x8*)(SM + ((t*512 + ko*2) ^ ((t&7)<<4)));
      }
#pragma unroll
      for (int n = 0; n < 4; ++n)
        bb[n] = *(const bf16x8*)(qkv_wb + jq[n]*256 + ko);
#pragma unroll
      for (int m = 0; m < 4; ++m)
#pragma unroll
        for (int n = 0; n < 4; ++n)
          acc[m][n] = MFMA16(a[m], bb[n], acc[m][n]);
    }
    float bj[4];
#pragma unroll
    for (int n = 0; n < 4; ++n) bj[n] = qkv_b[jq[n]];
#pragma unroll
    for (int m = 0; m < 4; ++m)
#pragma unroll
      for (int n = 0; n < 4; ++n)
#pragma unroll
        for (int r = 0; r < 4; ++r) acc[m][n][r] += bj[n];
    const float nqw0 = nq_w[lm], nqw1 = nq_w[16+lm];
    const float nkw0 = nk_w[lm], nkw1 = nk_w[16+lm];
#pragma unroll
    for (int m = 0; m < 4; ++m)
#pragma unroll
      for (int r = 0; r < 4; ++r) {
        float q0 = acc[m][0][r], q1 = acc[m][1][r];
        float k0 = acc[m][2][r], k1 = acc[m][3][r];
        float sq = q0*q0 + q1*q1, sk = k0*k0 + k1*k1;
        sq += __shfl_xor(sq, 1); sk += __shfl_xor(sk, 1);
        sq += __shfl_xor(sq, 2); sk += __shfl_xor(sk, 2);
        sq += __shfl_xor(sq, 4); sk += __shfl_xor(sk, 4);
        sq += __shfl_xor(sq, 8); sk += __shfl_xor(sk, 8);
        const float scq = rsqrtf(sq * (1.0f/32.0f) + 1.1920929e-07f);
        const float sck = rsqrtf(sk * (1.0f/32.0f) + 1.1920929e-07f);
        acc[m][0][r] = q0*scq*nqw0; acc[m][1][r] = q1*scq*nqw1;
        acc[m][2][r] = k0*sck*nkw0; acc[m][3][r] = k1*sck*nkw1;
      }
#pragma unroll
    for (int m = 0; m < 4; ++m)
#pragma unroll
      for (int n = 0; n < 2; ++n)
#pragma unroll
        for (int r = 0; r < 4; ++r)
          *(bf16*)(SM + SB + m*1024 + (lg*4+r)*16 + (n*2 + (lm>>3))*256 + (lm&7)*2)
            = (bf16)acc[m][n][r];
    FENCE();
#pragma unroll
    for (int m = 0; m < 4; ++m)
      qf[m] = *(const bf16x8*)(SM + SB + m*1024 + lane*16);
    FENCE();
#pragma unroll
    for (int m = 0; m < 4; ++m)
#pragma unroll
      for (int n = 0; n < 2; ++n)
#pragma unroll
        for (int r = 0; r < 4; ++r)
          *(bf16*)(SM + SB + m*1024 + (lg*4+r)*16 + (n*2 + (lm>>3))*256 + (lm&7)*2)
            = (bf16)acc[m][2+n][r];
    FENCE();
#pragma unroll
    for (int m = 0; m < 4; ++m)
      kf[m] = *(const bf16x8*)(SM + SB + m*1024 + lane*16);
    FENCE();
  }

  // ---- QKV pass1: v for this head
  {
    const int jv[2] = { 512 + h*32 + lm, 512 + h*32 + 16 + lm };
    f32x4 vacc[4][2] = {};
#pragma unroll
    for (int kk = 0; kk < 8; ++kk) {
      const int ko = kk*32 + lk;
      bf16x8 a[4], bb[2];
#pragma unroll
      for (int m = 0; m < 4; ++m) {
        const int t = m*16 + lm;
        a[m] = *(const bf16x8*)(SM + ((t*512 + ko*2) ^ ((t&7)<<4)));
      }
#pragma unroll
      for (int n = 0; n < 2; ++n)
        bb[n] = *(const bf16x8*)(qkv_wb + jv[n]*256 + ko);
#pragma unroll
      for (int m = 0; m < 4; ++m)
#pragma unroll
        for (int n = 0; n < 2; ++n)
          vacc[m][n] = MFMA16(a[m], bb[n], vacc[m][n]);
    }
    float bj[2] = { qkv_b[jv[0]], qkv_b[jv[1]] };
#pragma unroll
    for (int m = 0; m < 4; ++m)
#pragma unroll
      for (int n = 0; n < 2; ++n)
#pragma unroll
        for (int r = 0; r < 4; ++r)
          *(bf16*)(SM + SB + (n*2 + (m>>1))*1024 + lm*16
                   + ((m&1)*2 + ((lg*4+r)>>3))*256 + ((lg*4+r)&7)*2)
            = (bf16)(vacc[m][n][r] + bj[n]);
    FENCE();
#pragma unroll
    for (int nf = 0; nf < 2; ++nf)
#pragma unroll
      for (int ks = 0; ks < 2; ++ks)
        vb[nf][ks] = *(const bf16x8*)(SM + SB + (nf*2+ks)*1024 + lane*16);
    FENCE();
  }
  __syncthreads();   // B1

  // ---- QK^T + bias + mask + softmax (no-max: s <= ||q||*||k|| + 16 <= 48, exp-safe)
  f32x4 s[4][4];
#pragma unroll
  for (int m = 0; m < 4; ++m)
#pragma unroll
    for (int n = 0; n < 4; ++n) {
      f32x4 z = {};
      s[m][n] = MFMA16(qf[m], kf[n], z);
    }
#pragma unroll
  for (int n = 0; n < 4; ++n) {
    const int ct = n*16 + lm;
    const int idc = ((wy==7) ? (((ct>>3) < 4) ? 1 : 2) : 0) * 3
                  + ((wx==7) ? (((ct&7)  < 4) ? 1 : 2) : 0);
#pragma unroll
    for (int m = 0; m < 4; ++m) {
      const f32x4 bt = *(const f32x4*)(bias_t + h*4096 + ct*64 + m*16 + lg*4);
#pragma unroll
      for (int r = 0; r < 4; ++r) {
        const int rt = m*16 + lg*4 + r;
        const int idr = ((wy==7) ? (((rt>>3) < 4) ? 1 : 2) : 0) * 3
                      + ((wx==7) ? (((rt&7)  < 4) ? 1 : 2) : 0);
        float add = bt[r];
        if (idr != idc) add -= 100.0f;
        s[m][n][r] += add;
      }
    }
  }
#pragma unroll
  for (int m = 0; m < 4; ++m)
#pragma unroll
    for (int r = 0; r < 4; ++r) {
      float v0 = __expf(s[m][0][r]), v1 = __expf(s[m][1][r]);
      float v2 = __expf(s[m][2][r]), v3 = __expf(s[m][3][r]);
      float sm = v0 + v1 + v2 + v3;
      sm += __shfl_xor(sm, 1);
      sm += __shfl_xor(sm, 2);
      sm += __shfl_xor(sm, 4);
      sm += __shfl_xor(sm, 8);
      const float inv = 1.0f / sm;
      s[m][0][r] = v0*inv; s[m][1][r] = v1*inv; s[m][2][r] = v2*inv; s[m][3][r] = v3*inv;
    }

  // ---- PV through strip in two 32-row halves
  f32x4 yacc[4][2] = {};
#pragma unroll
  for (int mh = 0; mh < 2; ++mh) {
#pragma unroll
    for (int ml = 0; ml < 2; ++ml)
#pragma unroll
      for (int n = 0; n < 4; ++n)
#pragma unroll
        for (int r = 0; r < 4; ++r)
          *(bf16*)(SM + SB + (ml*2 + (n>>1))*1024 + (lg*4+r)*16
                   + ((n&1)*2 + (lm>>3))*256 + (lm&7)*2)
            = (bf16)s[mh*2+ml][n][r];
    FENCE();
    bf16x8 pa[2][2];
#pragma unroll
    for (int ml = 0; ml < 2; ++ml)
#pragma unroll
      for (int ks = 0; ks < 2; ++ks)
        pa[ml][ks] = *(const bf16x8*)(SM + SB + (ml*2+ks)*1024 + lane*16);
    FENCE();
#pragma unroll
    for (int ml = 0; ml < 2; ++ml)
#pragma unroll
      for (int ks = 0; ks < 2; ++ks)
#pragma unroll
        for (int nf = 0; nf < 2; ++nf)
          yacc[mh*2+ml][nf] = MFMA16(pa[ml][ks], vb[nf][ks], yacc[mh*2+ml][nf]);
  }

  // ---- y (head h) -> y_all in XA area
#pragma unroll
  for (int m = 0; m < 4; ++m)
#pragma unroll
    for (int nf = 0; nf < 2; ++nf)
#pragma unroll
      for (int r = 0; r < 4; ++r) {
        const int t = m*16 + lg*4 + r;
        const int c = h*32 + nf*16 + lm;
        *(bf16*)(SM + ((t*512 + c*2) ^ ((t&7)<<4))) = (bf16)yacc[m][nf][r];
      }
  __syncthreads();   // B2

  // ---- prefetch x residual (consumed after B4) -- covered by proj + LN1 stats
  float xr0[4][4], xr1[4][4];
#pragma unroll
  for (int m = 0; m < 4; ++m)
#pragma unroll
    for (int r = 0; r < 4; ++r) {
      const int row = m*16 + lg*4 + r;
      const int iy = row >> 3, ix = row & 7;
      const int gh = (wy*8 + iy + 4) & 63, gw = (wx*8 + ix + 4) & 63;
      const size_t gp = (size_t)(b*4096 + gh*64 + gw) * 256 + wv*32 + lm;
      xr0[m][r] = x[gp];
      xr1[m][r] = x[gp + 16];
    }

  // ---- proj: wave covers 32 cols, K=256
  f32x4 pacc[4][2] = {};
#pragma unroll
  for (int kk = 0; kk < 8; ++kk) {
    const int ko = kk*32 + lk;
    bf16x8 a[4], bb[2];
#pragma unroll
    for (int m = 0; m < 4; ++m) {
      const int t = m*16 + lm;
      a[m] = *(const bf16x8*)(SM + ((t*512 + ko*2) ^ ((t&7)<<4)));
    }
#pragma unroll
    for (int n = 0; n < 2; ++n) {
      const int j = wv*32 + n*16 + lm;
      bb[n] = *(const bf16x8*)(proj_wb + j*256 + ko);
    }
#pragma unroll
    for (int m = 0; m < 4; ++m)
#pragma unroll
      for (int n = 0; n < 2; ++n)
        pacc[m][n] = MFMA16(a[m], bb[n], pacc[m][n]);
  }
  {
    const float b0 = proj_b[wv*32 + lm], b1 = proj_b[wv*32 + 16 + lm];
#pragma unroll
    for (int m = 0; m < 4; ++m)
#pragma unroll
      for (int r = 0; r < 4; ++r) { pacc[m][0][r] += b0; pacc[m][1][r] += b1; }
  }

  // ---- LN1 stats (fragment reduce)
#pragma unroll
  for (int m = 0; m < 4; ++m)
#pragma unroll
    for (int r = 0; r < 4; ++r) {
      float p  = pacc[m][0][r] + pacc[m][1][r];
      float ps = pacc[m][0][r]*pacc[m][0][r] + pacc[m][1][r]*pacc[m][1][r];
      p  += __shfl_xor(p, 1);  ps += __shfl_xor(ps, 1);
      p  += __shfl_xor(p, 2);  ps += __shfl_xor(ps, 2);
      p  += __shfl_xor(p, 4);  ps += __shfl_xor(ps, 4);
      p  += __shfl_xor(p, 8);  ps += __shfl_xor(ps, 8);
      if (lm == 0) {
        const int row = m*16 + lg*4 + r;
        *(float*)(SM + LNB + row*32 + wv*4) = p;
        *(float*)(SM + LNB + 2048 + row*32 + wv*4) = ps;
      }
    }
  __syncthreads();   // B3
  if (tid < 64) {
    const int row = tid;
    f32x4 s0 = *(const f32x4*)(SM + LNB + row*32);
    f32x4 s1 = *(const f32x4*)(SM + LNB + row*32 + 16);
    f32x4 q0 = *(const f32x4*)(SM + LNB + 2048 + row*32);
    f32x4 q1 = *(const f32x4*)(SM + LNB + 2048 + row*32 + 16);
    const float sm_ = s0[0]+s0[1]+s0[2]+s0[3]+s1[0]+s1[1]+s1[2]+s1[3];
    const float qq  = q0[0]+q0[1]+q0[2]+q0[3]+q1[0]+q1[1]+q1[2]+q1[3];
    const float mu  = sm_ * (1.0f/256.0f);
    const float var = qq * (1.0f/256.0f) - mu*mu;
    float2 mi; mi.x = mu; mi.y = rsqrtf(var + 1e-5f);
    *(float2*)(SM + LNB + 4096 + row*8) = mi;
  }
  __syncthreads();   // B4

  // ---- LN1 apply + x shortcut (prefetched), x1 stays in pacc; bf16 copy -> XA
  // (no barrier needed before XA writes: all XA reads completed before B3,
  //  and LNB stats live in a disjoint LDS region)
  {
    const float w0 = n1w[wv*32 + lm],  w1 = n1w[wv*32 + 16 + lm];
    const float b0 = n1b[wv*32 + lm],  b1 = n1b[wv*32 + 16 + lm];
#pragma unroll
    for (int m = 0; m < 4; ++m)
#pragma unroll
      for (int r = 0; r < 4; ++r) {
        const int row = m*16 + lg*4 + r;
        const float2 mi = *(const float2*)(SM + LNB + 4096 + row*8);
        pacc[m][0][r] = (pacc[m][0][r] - mi.x)*mi.y*w0 + b0 + xr0[m][r];
        pacc[m][1][r] = (pacc[m][1][r] - mi.x)*mi.y*w1 + b1 + xr1[m][r];
      }
  }
#pragma unroll
  for (int m = 0; m < 4; ++m)
#pragma unroll
    for (int r = 0; r < 4; ++r) {
      const int t = m*16 + lg*4 + r;
      const int c0 = wv*32 + lm, c1 = wv*32 + 16 + lm;
      *(bf16*)(SM + ((t*512 + c0*2) ^ ((t&7)<<4))) = (bf16)pacc[m][0][r];
      *(bf16*)(SM + ((t*512 + c1*2) ^ ((t&7)<<4))) = (bf16)pacc[m][1][r];
    }
  __syncthreads();   // B5: XA = x1 bf16 ready; HS region free

  // ================= MLP phase (same 64 tokens, in-block) =================
  f32x4 acc2[4][2] = {};
#pragma unroll 1
  for (int kc = 0; kc < 4; ++kc) {
    f32x4 acc1[4][2] = {};
#pragma unroll
    for (int kk = 0; kk < 8; ++kk) {
      const int ko = kk*32 + lk;
      bf16x8 a[4], bb[2];
#pragma unroll
      for (int m = 0; m < 4; ++m) {
        const int t = m*16 + lm;
        a[m] = *(const bf16x8*)(SM + ((t*512 + ko*2) ^ ((t&7)<<4)));
      }
#pragma unroll
      for (int n = 0; n < 2; ++n) {
        const int j = kc*256 + wv*32 + n*16 + lm;
        bb[n] = *(const bf16x8*)(fc1_wb + j*256 + ko);
      }
#pragma unroll
      for (int m = 0; m < 4; ++m)
#pragma unroll
        for (int n = 0; n < 2; ++n)
          acc1[m][n] = MFMA16(a[m], bb[n], acc1[m][n]);
    }
    // fast GELU + bias -> HS
#pragma unroll
    for (int n = 0; n < 2; ++n) {
      const float bj = fc1_b[kc*256 + wv*32 + n*16 + lm];
      const int cb = wv*64 + n*32 + lm*2;
#pragma unroll
      for (int m = 0; m < 4; ++m)
#pragma unroll
        for (int r = 0; r < 4; ++r) {
          const int t = m*16 + lg*4 + r;
          const float v = gelu_fast(acc1[m][n][r] + bj);
          *(bf16*)(SM + HS + ((t*512 + cb) ^ ((t&7)<<4))) = (bf16)v;
        }
    }
    __syncthreads();
    // fc2 partial
#pragma unroll
    for (int kk = 0; kk < 8; ++kk) {
      const int ko = kk*32 + lk;
      bf16x8 a[4], bb[2];
#pragma unroll
      for (int m = 0; m < 4; ++m) {
        const int t = m*16 + lm;
        a[m] = *(const bf16x8*)(SM + HS + ((t*512 + ko*2) ^ ((t&7)<<4)));
      }
#pragma unroll
      for (int n = 0; n < 2; ++n) {
        const int j = wv*32 + n*16 + lm;
        bb[n] = *(const bf16x8*)(fc2_wb + (size_t)j*1024 + kc*256 + ko);
      }
#pragma unroll
      for (int m = 0; m < 4; ++m)
#pragma unroll
        for (int n = 0; n < 2; ++n)
          acc2[m][n] = MFMA16(a[m], bb[n], acc2[m][n]);
    }
    __syncthreads();
  }

  // fc2 bias
  {
    const float b0 = fc2_b[wv*32 + lm], b1 = fc2_b[wv*32 + 16 + lm];
#pragma unroll
    for (int m = 0; m < 4; ++m)
#pragma unroll
      for (int r = 0; r < 4; ++r) { acc2[m][0][r] += b0; acc2[m][1][r] += b1; }
  }

  // ---- LN2 stats
#pragma unroll
  for (int m = 0; m < 4; ++m)
#pragma unroll
    for (int r = 0; r < 4; ++r) {
      float p  = acc2[m][0][r] + acc2[m][1][r];
      float ps = acc2[m][0][r]*acc2[m][0][r] + acc2[m][1][r]*acc2[m][1][r];
      p  += __shfl_xor(p, 1);  ps += __shfl_xor(ps, 1);
      p  += __shfl_xor(p, 2);  ps += __shfl_xor(ps, 2);
      p  += __shfl_xor(p, 4);  ps += __shfl_xor(ps, 4);
      p  += __shfl_xor(p, 8);  ps += __shfl_xor(ps, 8);
      if (lm == 0) {
        const int row = m*16 + lg*4 + r;
        *(float*)(SM + LNB + row*32 + wv*4) = p;
        *(float*)(SM + LNB + 2048 + row*32 + wv*4) = ps;
      }
    }
  __syncthreads();
  if (tid < 64) {
    const int row = tid;
    f32x4 s0 = *(const f32x4*)(SM + LNB + row*32);
    f32x4 s1 = *(const f32x4*)(SM + LNB + row*32 + 16);
    f32x4 q0 = *(const f32x4*)(SM + LNB + 2048 + row*32);
    f32x4 q1 = *(const f32x4*)(SM + LNB + 2048 + row*32 + 16);
    const float sm_ = s0[0]+s0[1]+s0[2]+s0[3]+s1[0]+s1[1]+s1[2]+s1[3];
    const float qq  = q0[0]+q0[1]+q0[2]+q0[3]+q1[0]+q1[1]+q1[2]+q1[3];
    const float mu  = sm_ * (1.0f/256.0f);
    const float var = qq * (1.0f/256.0f) - mu*mu;
    float2 mi; mi.x = mu; mi.y = rsqrtf(var + 1e-5f);
    *(float2*)(SM + LNB + 4096 + row*8) = mi;
  }
  __syncthreads();

  // ---- LN2 apply + x1 residual (regs) -> DIRECT fragment store
  // (wave covers one aligned 128B line per row via its two 64B stores)
  {
    const float w0 = n2w[wv*32 + lm],  w1 = n2w[wv*32 + 16 + lm];
    const float b0 = n2b[wv*32 + lm],  b1 = n2b[wv*32 + 16 + lm];
#pragma unroll
    for (int m = 0; m < 4; ++m)
#pragma unroll
      for (int r = 0; r < 4; ++r) {
        const int row = m*16 + lg*4 + r;
        const float2 mi = *(const float2*)(SM + LNB + 4096 + row*8);
        const int iy = row >> 3, ix = row & 7;
        const int gh = (wy*8 + iy + 4) & 63, gw = (wx*8 + ix + 4) & 63;
        const size_t gp = (size_t)(b*4096 + gh*64 + gw) * 256 + wv*32 + lm;
        out[gp]      = (acc2[m][0][r] - mi.x)*mi.y*w0 + b0 + pacc[m][0][r];
        out[gp + 16] = (acc2[m][1][r] - mi.x)*mi.y*w1 + b1 + pacc[m][1][r];
      }
  }
}

extern "C" void kernel_launch(void* const* d_in, const int* in_sizes, int n_in,
                              void* d_out, int out_size, void* d_ws, size_t ws_size,
                              hipStream_t stream) {
  const float* x      = (const float*)d_in[0];
  const float* qkv_w  = (const float*)d_in[1];
  const float* qkv_b  = (const float*)d_in[2];
  const float* nq_w   = (const float*)d_in[3];
  const float* nk_w   = (const float*)d_in[4];
  const float* cpb_w1 = (const float*)d_in[5];
  const float* cpb_b1 = (const float*)d_in[6];
  const float* cpb_w2 = (const float*)d_in[7];
  const float* proj_w = (const float*)d_in[8];
  const float* proj_b = (const float*)d_in[9];
  const float* n1w    = (const float*)d_in[10];
  const float* n1b    = (const float*)d_in[11];
  const float* fc1_w  = (const float*)d_in[12];
  const float* fc1_b  = (const float*)d_in[13];
  const float* fc2_w  = (const float*)d_in[14];
  const float* fc2_b  = (const float*)d_in[15];
  const float* n2w    = (const float*)d_in[16];
  const float* n2b    = (const float*)d_in[17];

  char* ws = (char*)d_ws;
  bf16*  qkv_wb  = (bf16*) (ws);                   //   393216 B
  bf16*  proj_wb = (bf16*) (ws + 393216);          //   131072 B
  bf16*  fc1_wb  = (bf16*) (ws + 524288);          //   524288 B
  bf16*  fc2_wb  = (bf16*) (ws + 1048576);         //   524288 B
  float* bias_t  = (float*)(ws + 1572864);         //   131072 B
  float* tab_g   = (float*)(ws + 1703936);         //     7200 B

  prep_weights<<<1024, 256, 0, stream>>>(qkv_w, proj_w, fc1_w, fc2_w,
                                         qkv_wb, proj_wb, fc1_wb, fc2_wb);
  prep_tab<<<225, 64, 0, stream>>>(cpb_w1, cpb_b1, cpb_w2, tab_g);
  prep_expand<<<128, 256, 0, stream>>>(tab_g, bias_t);
  k_fused<<<512, 512, 0, stream>>>(x, qkv_wb, qkv_b, nq_w, nk_w,
                                   proj_wb, proj_b, n1w, n1b, bias_t,
                                   fc1_wb, fc1_b, fc2_wb, fc2_b, n2w, n2b,
                                   (float*)d_out);
}

// Round 21
// 173.828 us; speedup vs baseline: 1.0789x; 1.0037x over previous
//
#include <hip/hip_runtime.h>
#include <hip/hip_bf16.h>
#include <math.h>

typedef __bf16 bf16;
typedef bf16  bf16x8 __attribute__((ext_vector_type(8)));
typedef float f32x4  __attribute__((ext_vector_type(4)));

#define MFMA16(a,b,c) __builtin_amdgcn_mfma_f32_16x16x32_bf16(a,b,c,0,0,0)
#define FENCE() do { asm volatile("s_waitcnt lgkmcnt(0)" ::: "memory"); __builtin_amdgcn_sched_barrier(0); } while(0)

__device__ __forceinline__ f32x4 ld4(const float* p) { return *(const f32x4*)p; }

__device__ __forceinline__ bf16x8 cvt8(const f32x4& a, const f32x4& b) {
  bf16x8 v;
  v[0]=(bf16)a[0]; v[1]=(bf16)a[1]; v[2]=(bf16)a[2]; v[3]=(bf16)a[3];
  v[4]=(bf16)b[0]; v[5]=(bf16)b[1]; v[6]=(bf16)b[2]; v[7]=(bf16)b[3];
  return v;
}

// fast GELU (tanh form via HW exp)
__device__ __forceinline__ float gelu_fast(float x) {
  const float z = 1.5957691216f * (x + 0.044715f * x * x * x);
  return x / (1.0f + __expf(-z));
}

// ---------------- prep: fp32 weights -> bf16 ----------------
__global__ void prep_weights(const float* __restrict__ qkv_w, const float* __restrict__ proj_w,
                             const float* __restrict__ fc1_w, const float* __restrict__ fc2_w,
                             bf16* __restrict__ qkv_wb, bf16* __restrict__ proj_wb,
                             bf16* __restrict__ fc1_wb, bf16* __restrict__ fc2_wb) {
  int i = blockIdx.x * 256 + threadIdx.x;
  if (i < 196608) qkv_wb[i] = (bf16)qkv_w[i];
  if (i <  65536) proj_wb[i] = (bf16)proj_w[i];
  if (i < 262144) { fc1_wb[i] = (bf16)fc1_w[i]; fc2_wb[i] = (bf16)fc2_w[i]; }
}

// ---------------- prep: CPB MLP -> tab[225][8] ----------------
__global__ void prep_tab(const float* __restrict__ w1, const float* __restrict__ b1,
                         const float* __restrict__ w2, float* __restrict__ tab_g) {
  const int c = blockIdx.x;
  const int a = c / 15, bq = c % 15;
  const float g0 = (float)(a - 7) * (8.0f / 7.0f);
  const float g1 = (float)(bq - 7) * (8.0f / 7.0f);
  const float t0 = copysignf(log2f(fabsf(g0) + 1.0f) * (1.0f/3.0f), g0);
  const float t1 = copysignf(log2f(fabsf(g1) + 1.0f) * (1.0f/3.0f), g1);
  const int lane = threadIdx.x;
  float acc[8] = {0.f,0.f,0.f,0.f,0.f,0.f,0.f,0.f};
#pragma unroll
  for (int e = 0; e < 8; ++e) {
    const int h = lane*8 + e;
    float hv = t0 * w1[h*3 + 0] + t1 * w1[h*3 + 1] + b1[h];
    hv = fmaxf(hv, 0.0f);
#pragma unroll
    for (int j = 0; j < 8; ++j) acc[j] += hv * w2[j*512 + h];
  }
#pragma unroll
  for (int j = 0; j < 8; ++j) {
    acc[j] += __shfl_xor(acc[j], 1);
    acc[j] += __shfl_xor(acc[j], 2);
    acc[j] += __shfl_xor(acc[j], 4);
    acc[j] += __shfl_xor(acc[j], 8);
    acc[j] += __shfl_xor(acc[j], 16);
    acc[j] += __shfl_xor(acc[j], 32);
  }
  if (lane == 0) {
#pragma unroll
    for (int j = 0; j < 8; ++j) tab_g[c*8 + j] = acc[j];
  }
}

// ---------------- prep: expand tab -> bias_t[8][ct=64][rt=64] (TRANSPOSED) ----------------
__global__ void prep_expand(const float* __restrict__ tab_g, float* __restrict__ bias_t) {
  const int idx = blockIdx.x * 256 + threadIdx.x;
  const int head = idx >> 12, ct = (idx >> 6) & 63, rt = idx & 63;
  const int dy = (rt >> 3) - (ct >> 3), dx = (rt & 7) - (ct & 7);
  const float v = tab_g[((dy + 7)*15 + (dx + 7))*8 + head];
  bias_t[idx] = 16.0f / (1.0f + __expf(-v));
}

// ---------------- FULLY FUSED Swin block ----------------
// one block per (batch, window); 8 waves; wave = head. LDS 64KB (2 blocks/CU).
// launch_bounds min-BLOCKS=2 -> 128-VGPR budget.
__launch_bounds__(512, 2)
__global__ void k_fused(const float* __restrict__ x,
                        const bf16* __restrict__ qkv_wb, const float* __restrict__ qkv_b,
                        const float* __restrict__ nq_w, const float* __restrict__ nk_w,
                        const bf16* __restrict__ proj_wb, const float* __restrict__ proj_b,
                        const float* __restrict__ n1w, const float* __restrict__ n1b,
                        const float* __restrict__ bias_t,
                        const bf16* __restrict__ fc1_wb, const float* __restrict__ fc1_b,
                        const bf16* __restrict__ fc2_wb, const float* __restrict__ fc2_b,
                        const float* __restrict__ n2w, const float* __restrict__ n2b,
                        float* __restrict__ out) {
  __shared__ __align__(16) unsigned char SM[65536];
  const int tid  = threadIdx.x;
  const int wv   = tid >> 6;
  const int lane = tid & 63;
  const int lm   = lane & 15;
  const int lg   = lane >> 4;
  const int lk   = lg << 3;
  const int blk  = blockIdx.x;
  const int b    = blk >> 6;
  const int win  = blk & 63;
  const int wy   = win >> 3, wx = win & 7;
  const int h    = wv;
  const int SB   = 32768 + wv*4096;   // wave-private 4KB bounce strip
  const int LNB  = 32768;             // LN stats overlay (strips / HS region)
  const int HS   = 32768;             // MLP h-chunk buffer

  // ---- stage shifted-window x tile -> bf16 LDS [64][256] XOR-swizzled (XA = 0..32K)
  {
    const int t = tid >> 3, q8 = tid & 7;
    const int iy = t >> 3, ix = t & 7;
    const int gh = (wy*8 + iy + 4) & 63, gw = (wx*8 + ix + 4) & 63;
    const float* src = x + (size_t)(b*4096 + gh*64 + gw) * 256 + q8*32;
#pragma unroll
    for (int i = 0; i < 4; ++i) {
      f32x4 f0 = ld4(src + i*8);
      f32x4 f1 = ld4(src + i*8 + 4);
      *(bf16x8*)(SM + ((t*512 + (q8*32 + i*8)*2) ^ ((t&7)<<4))) = cvt8(f0, f1);
    }
  }
  __syncthreads();   // B0

  bf16x8 qf[4], kf[4], vb[2][2];

  // ---- QKV pass0: q + k (d 0..32) for this head
  {
    const int jq[4] = { h*32 + lm, h*32 + 16 + lm, 256 + h*32 + lm, 256 + h*32 + 16 + lm };
    f32x4 acc[4][4] = {};
#pragma unroll
    for (int kk = 0; kk < 8; ++kk) {
      const int ko = kk*32 + lk;
      bf16x8 a[4], bb[4];
#pragma unroll
      for (int m = 0; m < 4; ++m) {
        const int t = m*16 + lm;
        a[m] = *(const bf16x8*)(SM + ((t*512 + ko*2) ^ ((t&7)<<4)));
      }
#pragma unroll
      for (int n = 0; n < 4; ++n)
        bb[n] = *(const bf16x8*)(qkv_wb + jq[n]*256 + ko);
#pragma unroll
      for (int m = 0; m < 4; ++m)
#pragma unroll
        for (int n = 0; n < 4; ++n)
          acc[m][n] = MFMA16(a[m], bb[n], acc[m][n]);
    }
    float bj[4];
#pragma unroll
    for (int n = 0; n < 4; ++n) bj[n] = qkv_b[jq[n]];
#pragma unroll
    for (int m = 0; m < 4; ++m)
#pragma unroll
      for (int n = 0; n < 4; ++n)
#pragma unroll
        for (int r = 0; r < 4; ++r) acc[m][n][r] += bj[n];
    const float nqw0 = nq_w[lm], nqw1 = nq_w[16+lm];
    const float nkw0 = nk_w[lm], nkw1 = nk_w[16+lm];
#pragma unroll
    for (int m = 0; m < 4; ++m)
#pragma unroll
      for (int r = 0; r < 4; ++r) {
        float q0 = acc[m][0][r], q1 = acc[m][1][r];
        float k0 = acc[m][2][r], k1 = acc[m][3][r];
        float sq = q0*q0 + q1*q1, sk = k0*k0 + k1*k1;
        sq += __shfl_xor(sq, 1); sk += __shfl_xor(sk, 1);
        sq += __shfl_xor(sq, 2); sk += __shfl_xor(sk, 2);
        sq += __shfl_xor(sq, 4); sk += __shfl_xor(sk, 4);
        sq += __shfl_xor(sq, 8); sk += __shfl_xor(sk, 8);
        const float scq = rsqrtf(sq * (1.0f/32.0f) + 1.1920929e-07f);
        const float sck = rsqrtf(sk * (1.0f/32.0f) + 1.1920929e-07f);
        acc[m][0][r] = q0*scq*nqw0; acc[m][1][r] = q1*scq*nqw1;
        acc[m][2][r] = k0*sck*nkw0; acc[m][3][r] = k1*sck*nkw1;
      }
#pragma unroll
    for (int m = 0; m < 4; ++m)
#pragma unroll
      for (int n = 0; n < 2; ++n)
#pragma unroll
        for (int r = 0; r < 4; ++r)
          *(bf16*)(SM + SB + m*1024 + (lg*4+r)*16 + (n*2 + (lm>>3))*256 + (lm&7)*2)
            = (bf16)acc[m][n][r];
    FENCE();
#pragma unroll
    for (int m = 0; m < 4; ++m)
      qf[m] = *(const bf16x8*)(SM + SB + m*1024 + lane*16);
    FENCE();
#pragma unroll
    for (int m = 0; m < 4; ++m)
#pragma unroll
      for (int n = 0; n < 2; ++n)
#pragma unroll
        for (int r = 0; r < 4; ++r)
          *(bf16*)(SM + SB + m*1024 + (lg*4+r)*16 + (n*2 + (lm>>3))*256 + (lm&7)*2)
            = (bf16)acc[m][2+n][r];
    FENCE();
#pragma unroll
    for (int m = 0; m < 4; ++m)
      kf[m] = *(const bf16x8*)(SM + SB + m*1024 + lane*16);
    FENCE();
  }

  // ---- QKV pass1: v for this head
  {
    const int jv[2] = { 512 + h*32 + lm, 512 + h*32 + 16 + lm };
    f32x4 vacc[4][2] = {};
#pragma unroll
    for (int kk = 0; kk < 8; ++kk) {
      const int ko = kk*32 + lk;
      bf16x8 a[4], bb[2];
#pragma unroll
      for (int m = 0; m < 4; ++m) {
        const int t = m*16 + lm;
        a[m] = *(const bf16x8*)(SM + ((t*512 + ko*2) ^ ((t&7)<<4)));
      }
#pragma unroll
      for (int n = 0; n < 2; ++n)
        bb[n] = *(const bf16x8*)(qkv_wb + jv[n]*256 + ko);
#pragma unroll
      for (int m = 0; m < 4; ++m)
#pragma unroll
        for (int n = 0; n < 2; ++n)
          vacc[m][n] = MFMA16(a[m], bb[n], vacc[m][n]);
    }
    float bj[2] = { qkv_b[jv[0]], qkv_b[jv[1]] };
#pragma unroll
    for (int m = 0; m < 4; ++m)
#pragma unroll
      for (int n = 0; n < 2; ++n)
#pragma unroll
        for (int r = 0; r < 4; ++r)
          *(bf16*)(SM + SB + (n*2 + (m>>1))*1024 + lm*16
                   + ((m&1)*2 + ((lg*4+r)>>3))*256 + ((lg*4+r)&7)*2)
            = (bf16)(vacc[m][n][r] + bj[n]);
    FENCE();
#pragma unroll
    for (int nf = 0; nf < 2; ++nf)
#pragma unroll
      for (int ks = 0; ks < 2; ++ks)
        vb[nf][ks] = *(const bf16x8*)(SM + SB + (nf*2+ks)*1024 + lane*16);
    FENCE();
  }
  __syncthreads();   // B1

  // ---- QK^T + bias + mask + softmax (no-max: s <= ||q||*||k|| + 16 <= 48, exp-safe)
  f32x4 s[4][4];
#pragma unroll
  for (int m = 0; m < 4; ++m)
#pragma unroll
    for (int n = 0; n < 4; ++n) {
      f32x4 z = {};
      s[m][n] = MFMA16(qf[m], kf[n], z);
    }
#pragma unroll
  for (int n = 0; n < 4; ++n) {
    const int ct = n*16 + lm;
    const int idc = ((wy==7) ? (((ct>>3) < 4) ? 1 : 2) : 0) * 3
                  + ((wx==7) ? (((ct&7)  < 4) ? 1 : 2) : 0);
#pragma unroll
    for (int m = 0; m < 4; ++m) {
      const f32x4 bt = *(const f32x4*)(bias_t + h*4096 + ct*64 + m*16 + lg*4);
#pragma unroll
      for (int r = 0; r < 4; ++r) {
        const int rt = m*16 + lg*4 + r;
        const int idr = ((wy==7) ? (((rt>>3) < 4) ? 1 : 2) : 0) * 3
                      + ((wx==7) ? (((rt&7)  < 4) ? 1 : 2) : 0);
        float add = bt[r];
        if (idr != idc) add -= 100.0f;
        s[m][n][r] += add;
      }
    }
  }
#pragma unroll
  for (int m = 0; m < 4; ++m)
#pragma unroll
    for (int r = 0; r < 4; ++r) {
      float v0 = __expf(s[m][0][r]), v1 = __expf(s[m][1][r]);
      float v2 = __expf(s[m][2][r]), v3 = __expf(s[m][3][r]);
      float sm = v0 + v1 + v2 + v3;
      sm += __shfl_xor(sm, 1);
      sm += __shfl_xor(sm, 2);
      sm += __shfl_xor(sm, 4);
      sm += __shfl_xor(sm, 8);
      const float inv = __builtin_amdgcn_rcpf(sm);
      s[m][0][r] = v0*inv; s[m][1][r] = v1*inv; s[m][2][r] = v2*inv; s[m][3][r] = v3*inv;
    }

  // ---- PV through strip in two 32-row halves
  f32x4 yacc[4][2] = {};
#pragma unroll
  for (int mh = 0; mh < 2; ++mh) {
#pragma unroll
    for (int ml = 0; ml < 2; ++ml)
#pragma unroll
      for (int n = 0; n < 4; ++n)
#pragma unroll
        for (int r = 0; r < 4; ++r)
          *(bf16*)(SM + SB + (ml*2 + (n>>1))*1024 + (lg*4+r)*16
                   + ((n&1)*2 + (lm>>3))*256 + (lm&7)*2)
            = (bf16)s[mh*2+ml][n][r];
    FENCE();
    bf16x8 pa[2][2];
#pragma unroll
    for (int ml = 0; ml < 2; ++ml)
#pragma unroll
      for (int ks = 0; ks < 2; ++ks)
        pa[ml][ks] = *(const bf16x8*)(SM + SB + (ml*2+ks)*1024 + lane*16);
    FENCE();
#pragma unroll
    for (int ml = 0; ml < 2; ++ml)
#pragma unroll
      for (int ks = 0; ks < 2; ++ks)
#pragma unroll
        for (int nf = 0; nf < 2; ++nf)
          yacc[mh*2+ml][nf] = MFMA16(pa[ml][ks], vb[nf][ks], yacc[mh*2+ml][nf]);
  }

  // ---- y (head h) -> y_all in XA area
#pragma unroll
  for (int m = 0; m < 4; ++m)
#pragma unroll
    for (int nf = 0; nf < 2; ++nf)
#pragma unroll
      for (int r = 0; r < 4; ++r) {
        const int t = m*16 + lg*4 + r;
        const int c = h*32 + nf*16 + lm;
        *(bf16*)(SM + ((t*512 + c*2) ^ ((t&7)<<4))) = (bf16)yacc[m][nf][r];
      }
  __syncthreads();   // B2

  // ---- prefetch x residual (consumed after B4) -- covered by proj + LN1 stats
  float xr0[4][4], xr1[4][4];
#pragma unroll
  for (int m = 0; m < 4; ++m)
#pragma unroll
    for (int r = 0; r < 4; ++r) {
      const int row = m*16 + lg*4 + r;
      const int iy = row >> 3, ix = row & 7;
      const int gh = (wy*8 + iy + 4) & 63, gw = (wx*8 + ix + 4) & 63;
      const size_t gp = (size_t)(b*4096 + gh*64 + gw) * 256 + wv*32 + lm;
      xr0[m][r] = x[gp];
      xr1[m][r] = x[gp + 16];
    }

  // ---- proj: wave covers 32 cols, K=256
  f32x4 pacc[4][2] = {};
#pragma unroll
  for (int kk = 0; kk < 8; ++kk) {
    const int ko = kk*32 + lk;
    bf16x8 a[4], bb[2];
#pragma unroll
    for (int m = 0; m < 4; ++m) {
      const int t = m*16 + lm;
      a[m] = *(const bf16x8*)(SM + ((t*512 + ko*2) ^ ((t&7)<<4)));
    }
#pragma unroll
    for (int n = 0; n < 2; ++n) {
      const int j = wv*32 + n*16 + lm;
      bb[n] = *(const bf16x8*)(proj_wb + j*256 + ko);
    }
#pragma unroll
    for (int m = 0; m < 4; ++m)
#pragma unroll
      for (int n = 0; n < 2; ++n)
        pacc[m][n] = MFMA16(a[m], bb[n], pacc[m][n]);
  }
  {
    const float b0 = proj_b[wv*32 + lm], b1 = proj_b[wv*32 + 16 + lm];
#pragma unroll
    for (int m = 0; m < 4; ++m)
#pragma unroll
      for (int r = 0; r < 4; ++r) { pacc[m][0][r] += b0; pacc[m][1][r] += b1; }
  }

  // ---- LN1 stats (fragment reduce)
#pragma unroll
  for (int m = 0; m < 4; ++m)
#pragma unroll
    for (int r = 0; r < 4; ++r) {
      float p  = pacc[m][0][r] + pacc[m][1][r];
      float ps = pacc[m][0][r]*pacc[m][0][r] + pacc[m][1][r]*pacc[m][1][r];
      p  += __shfl_xor(p, 1);  ps += __shfl_xor(ps, 1);
      p  += __shfl_xor(p, 2);  ps += __shfl_xor(ps, 2);
      p  += __shfl_xor(p, 4);  ps += __shfl_xor(ps, 4);
      p  += __shfl_xor(p, 8);  ps += __shfl_xor(ps, 8);
      if (lm == 0) {
        const int row = m*16 + lg*4 + r;
        *(float*)(SM + LNB + row*32 + wv*4) = p;
        *(float*)(SM + LNB + 2048 + row*32 + wv*4) = ps;
      }
    }
  __syncthreads();   // B3
  if (tid < 64) {
    const int row = tid;
    f32x4 s0 = *(const f32x4*)(SM + LNB + row*32);
    f32x4 s1 = *(const f32x4*)(SM + LNB + row*32 + 16);
    f32x4 q0 = *(const f32x4*)(SM + LNB + 2048 + row*32);
    f32x4 q1 = *(const f32x4*)(SM + LNB + 2048 + row*32 + 16);
    const float sm_ = s0[0]+s0[1]+s0[2]+s0[3]+s1[0]+s1[1]+s1[2]+s1[3];
    const float qq  = q0[0]+q0[1]+q0[2]+q0[3]+q1[0]+q1[1]+q1[2]+q1[3];
    const float mu  = sm_ * (1.0f/256.0f);
    const float var = qq * (1.0f/256.0f) - mu*mu;
    float2 mi; mi.x = mu; mi.y = rsqrtf(var + 1e-5f);
    *(float2*)(SM + LNB + 4096 + row*8) = mi;
  }
  __syncthreads();   // B4

  // ---- LN1 apply + x shortcut (prefetched), x1 stays in pacc; bf16 copy -> XA
  {
    const float w0 = n1w[wv*32 + lm],  w1 = n1w[wv*32 + 16 + lm];
    const float b0 = n1b[wv*32 + lm],  b1 = n1b[wv*32 + 16 + lm];
#pragma unroll
    for (int m = 0; m < 4; ++m)
#pragma unroll
      for (int r = 0; r < 4; ++r) {
        const int row = m*16 + lg*4 + r;
        const float2 mi = *(const float2*)(SM + LNB + 4096 + row*8);
        pacc[m][0][r] = (pacc[m][0][r] - mi.x)*mi.y*w0 + b0 + xr0[m][r];
        pacc[m][1][r] = (pacc[m][1][r] - mi.x)*mi.y*w1 + b1 + xr1[m][r];
      }
  }
#pragma unroll
  for (int m = 0; m < 4; ++m)
#pragma unroll
    for (int r = 0; r < 4; ++r) {
      const int t = m*16 + lg*4 + r;
      const int c0 = wv*32 + lm, c1 = wv*32 + 16 + lm;
      *(bf16*)(SM + ((t*512 + c0*2) ^ ((t&7)<<4))) = (bf16)pacc[m][0][r];
      *(bf16*)(SM + ((t*512 + c1*2) ^ ((t&7)<<4))) = (bf16)pacc[m][1][r];
    }
  __syncthreads();   // B5: XA = x1 bf16 ready; HS region free

  // ================= MLP phase (same 64 tokens, in-block) =================
  f32x4 acc2[4][2] = {};
#pragma unroll 1
  for (int kc = 0; kc < 4; ++kc) {
    f32x4 acc1[4][2] = {};
#pragma unroll
    for (int kk = 0; kk < 8; ++kk) {
      const int ko = kk*32 + lk;
      bf16x8 a[4], bb[2];
#pragma unroll
      for (int m = 0; m < 4; ++m) {
        const int t = m*16 + lm;
        a[m] = *(const bf16x8*)(SM + ((t*512 + ko*2) ^ ((t&7)<<4)));
      }
#pragma unroll
      for (int n = 0; n < 2; ++n) {
        const int j = kc*256 + wv*32 + n*16 + lm;
        bb[n] = *(const bf16x8*)(fc1_wb + j*256 + ko);
      }
#pragma unroll
      for (int m = 0; m < 4; ++m)
#pragma unroll
        for (int n = 0; n < 2; ++n)
          acc1[m][n] = MFMA16(a[m], bb[n], acc1[m][n]);
    }
    // fast GELU + bias -> HS
#pragma unroll
    for (int n = 0; n < 2; ++n) {
      const float bj = fc1_b[kc*256 + wv*32 + n*16 + lm];
      const int cb = wv*64 + n*32 + lm*2;
#pragma unroll
      for (int m = 0; m < 4; ++m)
#pragma unroll
        for (int r = 0; r < 4; ++r) {
          const int t = m*16 + lg*4 + r;
          const float v = gelu_fast(acc1[m][n][r] + bj);
          *(bf16*)(SM + HS + ((t*512 + cb) ^ ((t&7)<<4))) = (bf16)v;
        }
    }
    __syncthreads();
    // fc2 partial
#pragma unroll
    for (int kk = 0; kk < 8; ++kk) {
      const int ko = kk*32 + lk;
      bf16x8 a[4], bb[2];
#pragma unroll
      for (int m = 0; m < 4; ++m) {
        const int t = m*16 + lm;
        a[m] = *(const bf16x8*)(SM + HS + ((t*512 + ko*2) ^ ((t&7)<<4)));
      }
#pragma unroll
      for (int n = 0; n < 2; ++n) {
        const int j = wv*32 + n*16 + lm;
        bb[n] = *(const bf16x8*)(fc2_wb + (size_t)j*1024 + kc*256 + ko);
      }
#pragma unroll
      for (int m = 0; m < 4; ++m)
#pragma unroll
        for (int n = 0; n < 2; ++n)
          acc2[m][n] = MFMA16(a[m], bb[n], acc2[m][n]);
    }
    __syncthreads();
  }

  // fc2 bias
  {
    const float b0 = fc2_b[wv*32 + lm], b1 = fc2_b[wv*32 + 16 + lm];
#pragma unroll
    for (int m = 0; m < 4; ++m)
#pragma unroll
      for (int r = 0; r < 4; ++r) { acc2[m][0][r] += b0; acc2[m][1][r] += b1; }
  }

  // ---- LN2 stats
#pragma unroll
  for (int m = 0; m < 4; ++m)
#pragma unroll
    for (int r = 0; r < 4; ++r) {
      float p  = acc2[m][0][r] + acc2[m][1][r];
      float ps = acc2[m][0][r]*acc2[m][0][r] + acc2[m][1][r]*acc2[m][1][r];
      p  += __shfl_xor(p, 1);  ps += __shfl_xor(ps, 1);
      p  += __shfl_xor(p, 2);  ps += __shfl_xor(ps, 2);
      p  += __shfl_xor(p, 4);  ps += __shfl_xor(ps, 4);
      p  += __shfl_xor(p, 8);  ps += __shfl_xor(ps, 8);
      if (lm == 0) {
        const int row = m*16 + lg*4 + r;
        *(float*)(SM + LNB + row*32 + wv*4) = p;
        *(float*)(SM + LNB + 2048 + row*32 + wv*4) = ps;
      }
    }
  __syncthreads();
  if (tid < 64) {
    const int row = tid;
    f32x4 s0 = *(const f32x4*)(SM + LNB + row*32);
    f32x4 s1 = *(const f32x4*)(SM + LNB + row*32 + 16);
    f32x4 q0 = *(const f32x4*)(SM + LNB + 2048 + row*32);
    f32x4 q1 = *(const f32x4*)(SM + LNB + 2048 + row*32 + 16);
    const float sm_ = s0[0]+s0[1]+s0[2]+s0[3]+s1[0]+s1[1]+s1[2]+s1[3];
    const float qq  = q0[0]+q0[1]+q0[2]+q0[3]+q1[0]+q1[1]+q1[2]+q1[3];
    const float mu  = sm_ * (1.0f/256.0f);
    const float var = qq * (1.0f/256.0f) - mu*mu;
    float2 mi; mi.x = mu; mi.y = rsqrtf(var + 1e-5f);
    *(float2*)(SM + LNB + 4096 + row*8) = mi;
  }
  __syncthreads();

  // ---- LN2 apply + x1 residual (regs) -> DIRECT fragment store
  {
    const float w0 = n2w[wv*32 + lm],  w1 = n2w[wv*32 + 16 + lm];
    const float b0 = n2b[wv*32 + lm],  b1 = n2b[wv*32 + 16 + lm];
#pragma unroll
    for (int m = 0; m < 4; ++m)
#pragma unroll
      for (int r = 0; r < 4; ++r) {
        const int row = m*16 + lg*4 + r;
        const float2 mi = *(const float2*)(SM + LNB + 4096 + row*8);
        const int iy = row >> 3, ix = row & 7;
        const int gh = (wy*8 + iy + 4) & 63, gw = (wx*8 + ix + 4) & 63;
        const size_t gp = (size_t)(b*4096 + gh*64 + gw) * 256 + wv*32 + lm;
        out[gp]      = (acc2[m][0][r] - mi.x)*mi.y*w0 + b0 + pacc[m][0][r];
        out[gp + 16] = (acc2[m][1][r] - mi.x)*mi.y*w1 + b1 + pacc[m][1][r];
      }
  }
}

extern "C" void kernel_launch(void* const* d_in, const int* in_sizes, int n_in,
                              void* d_out, int out_size, void* d_ws, size_t ws_size,
                              hipStream_t stream) {
  const float* x      = (const float*)d_in[0];
  const float* qkv_w  = (const float*)d_in[1];
  const float* qkv_b  = (const float*)d_in[2];
  const float* nq_w   = (const float*)d_in[3];
  const float* nk_w   = (const float*)d_in[4];
  const float* cpb_w1 = (const float*)d_in[5];
  const float* cpb_b1 = (const float*)d_in[6];
  const float* cpb_w2 = (const float*)d_in[7];
  const float* proj_w = (const float*)d_in[8];
  const float* proj_b = (const float*)d_in[9];
  const float* n1w    = (const float*)d_in[10];
  const float* n1b    = (const float*)d_in[11];
  const float* fc1_w  = (const float*)d_in[12];
  const float* fc1_b  = (const float*)d_in[13];
  const float* fc2_w  = (const float*)d_in[14];
  const float* fc2_b  = (const float*)d_in[15];
  const float* n2w    = (const float*)d_in[16];
  const float* n2b    = (const float*)d_in[17];

  char* ws = (char*)d_ws;
  bf16*  qkv_wb  = (bf16*) (ws);                   //   393216 B
  bf16*  proj_wb = (bf16*) (ws + 393216);          //   131072 B
  bf16*  fc1_wb  = (bf16*) (ws + 524288);          //   524288 B
  bf16*  fc2_wb  = (bf16*) (ws + 1048576);         //   524288 B
  float* bias_t  = (float*)(ws + 1572864);         //   131072 B
  float* tab_g   = (float*)(ws + 1703936);         //     7200 B

  prep_weights<<<1024, 256, 0, stream>>>(qkv_w, proj_w, fc1_w, fc2_w,
                                         qkv_wb, proj_wb, fc1_wb, fc2_wb);
  prep_tab<<<225, 64, 0, stream>>>(cpb_w1, cpb_b1, cpb_w2, tab_g);
  prep_expand<<<128, 256, 0, stream>>>(tab_g, bias_t);
  k_fused<<<512, 512, 0, stream>>>(x, qkv_wb, qkv_b, nq_w, nk_w,
                                   proj_wb, proj_b, n1w, n1b, bias_t,
                                   fc1_wb, fc1_b, fc2_wb, fc2_b, n2w, n2b,
                                   (float*)d_out);
}